// Round 10
// baseline (5425.993 us; speedup 1.0000x reference)
//
#include <hip/hip_runtime.h>
#include <hip/hip_bf16.h>
#include <cstdint>
#include <cstddef>

typedef __hip_bfloat16 bf16;

#define GXC 100
#define GYC 100
#define GZC 20
#define NCELL (GXC*GYC*GZC)
#define MAXVX 60000
#define CAP 12

static inline int cdiv(int a, int b){ return (a+b-1)/b; }

__device__ __forceinline__ float b2f(bf16 v){ return __bfloat162float(v); }
__device__ __forceinline__ void unpk2(unsigned u, float& lo, float& hi){
  union { unsigned q; float f; } a, b;
  a.q = u << 16; b.q = u & 0xFFFF0000u;
  lo = a.f; hi = b.f;
}
__device__ __forceinline__ void loadA8(const bf16* p, float* av){
  const uint4 u = *(const uint4*)p;
  unpk2(u.x, av[0], av[1]); unpk2(u.y, av[2], av[3]);
  unpk2(u.z, av[4], av[5]); unpk2(u.w, av[6], av[7]);
}
__device__ __forceinline__ void loadA8f(const float* p, float* av){
  const float4 u0 = *(const float4*)p;
  const float4 u1 = *((const float4*)p + 1);
  av[0]=u0.x; av[1]=u0.y; av[2]=u0.z; av[3]=u0.w;
  av[4]=u1.x; av[5]=u1.y; av[6]=u1.z; av[7]=u1.w;
}

// ---------- params gather (all f32 inputs) ----------
struct P22 { const float* p[22]; };
__global__ void k_params(P22 ps, float* __restrict__ prm)
{
  const int ns[22] = {160,32,32,32,4096,128,128,128,64,64,128,128,128,128,256,256,512,512,512,256,256,256};
  int off = 0;
  for (int e=0;e<22;++e){
    const float* s = ps.p[e];
    const int n = ns[e];
    for (int i=threadIdx.x;i<n;i+=256) prm[off+i] = s[i];
    off += n;
  }
}
#define O_V1W 0
#define O_V1B 160
#define O_V1G 192
#define O_V1BT 224
#define O_V2W 256
#define O_V2B 4352
#define O_V2G 4480
#define O_V2BT 4608
#define O_SP1G 4736
#define O_SP1B 4800
#define O_SP2G 4864
#define O_SP2B 4992
#define O_SP3G 5120
#define O_SP3B 5248
#define O_SP4G 5376
#define O_SP4B 5632
#define O_BV1B 5888
#define O_BV1G 6400
#define O_BV1BT 6912
#define O_BV2B 7424
#define O_BV2G 7680
#define O_BV2BT 7936

// ---------- voxelize pass 1: per-cell counts ----------
__global__ void k_points(const float* __restrict__ pts, int N,
                         unsigned* __restrict__ cnt, unsigned* __restrict__ counters)
{
  const int i = blockIdx.x*256 + threadIdx.x;
  if (i >= N) return;
  float x = pts[(size_t)i*5+0];
  float y = pts[(size_t)i*5+1];
  float z = pts[(size_t)i*5+2];
  float qx = (x - (-51.2f)) / 1.024f;
  float qy = (y - (-51.2f)) / 1.024f;
  float qz = (z - (-5.0f))  / 0.4f;
  int gx=(int)floorf(qx), gy=(int)floorf(qy), gz=(int)floorf(qz);
  if (x == 0.0f) return;
  if (gx<0||gx>=GXC||gy<0||gy>=GYC||gz<0||gz>=GZC) return;
  atomicAdd(&cnt[gx*(GYC*GZC) + gy*GZC + gz], 1u);
  atomicAdd(counters+4, 1u);
}

// ---------- rank occupied cells (cell-id order), first MAXVX kept ----------
__global__ __launch_bounds__(1024) void k_rank(const unsigned* __restrict__ cnt,
                                               int* __restrict__ keptList,
                                               int* __restrict__ map,
                                               unsigned* __restrict__ counters)
{
  __shared__ int wsum[16];
  __shared__ int sbase;
  const int tid = threadIdx.x;
  const int lane = tid & 63;
  const int w = tid >> 6;
  if (tid==0) sbase = 0;
  __syncthreads();
  for (int c0=0; c0<NCELL; c0+=1024){
    const int cell = c0 + tid;
    const int fl = (cell<NCELL && cnt[cell]>0u) ? 1 : 0;
    const unsigned long long m = __ballot(fl);
    const int wp = __popcll(m & ((1ull<<lane)-1ull));
    if (lane==0) wsum[w] = __popcll(m);
    __syncthreads();
    int wbase = 0;
    #pragma unroll
    for (int j=0;j<16;++j) wbase += (j<w) ? wsum[j] : 0;
    const int rank = sbase + wbase + wp;
    if (fl && rank < MAXVX){
      keptList[rank] = cell;
      const int ix=cell/2000, iy=(cell/20)%100, iz=cell%20;
      map[(iz*GYC+iy)*GXC+ix] = rank;
    }
    __syncthreads();
    if (tid==0){ int tot=0; for (int j=0;j<16;++j) tot+=wsum[j]; sbase+=tot; }
    __syncthreads();
  }
  if (tid==0) counters[0] = (unsigned)(sbase < MAXVX ? sbase : MAXVX);
}

// ---------- voxelize pass 2: collect point indices per kept voxel ----------
__global__ void k_points2(const float* __restrict__ pts, int N,
                          const int* __restrict__ map,
                          unsigned* __restrict__ scnt, int* __restrict__ slots)
{
  const int i = blockIdx.x*256 + threadIdx.x;
  if (i >= N) return;
  float x = pts[(size_t)i*5+0];
  float y = pts[(size_t)i*5+1];
  float z = pts[(size_t)i*5+2];
  float qx = (x - (-51.2f)) / 1.024f;
  float qy = (y - (-51.2f)) / 1.024f;
  float qz = (z - (-5.0f))  / 0.4f;
  int gx=(int)floorf(qx), gy=(int)floorf(qy), gz=(int)floorf(qz);
  if (x == 0.0f) return;
  if (gx<0||gx>=GXC||gy<0||gy>=GYC||gz<0||gz>=GZC) return;
  const int didx = (gz*GYC+gy)*GXC+gx;
  const int r = map[didx];
  if (r < 0) return;
  unsigned pos = atomicAdd(&scnt[r], 1u);
  if (pos < CAP) slots[r*CAP + pos] = i;
}

// ---------- z128: VFE response to an all-zero point row ----------
__global__ void k_z128(const float* __restrict__ prm, float* __restrict__ z128)
{
  __shared__ float h1[32];
  const int tid = threadIdx.x;   // 128
  if (tid<32){ float s = prm[O_V1B+tid]*prm[O_V1G+tid]+prm[O_V1BT+tid]; h1[tid]=s>0.f?s:0.f; }
  __syncthreads();
  float s = prm[O_V2B+tid];
  for (int j=0;j<32;++j) s += prm[O_V2W+tid*32+j]*h1[j];
  s = s*prm[O_V2G+tid] + prm[O_V2BT+tid];
  z128[tid] = s>0.f?s:0.f;
}

__global__ __launch_bounds__(128) void k_vfe(
  const float* __restrict__ pts, const float* __restrict__ prm,
  const unsigned* __restrict__ scnt, const int* __restrict__ slots,
  const int* __restrict__ keptList, const unsigned* __restrict__ counters,
  const float* __restrict__ z128,
  bf16* __restrict__ F0c, unsigned char* __restrict__ m0,
  int* __restrict__ list0, unsigned* __restrict__ cdbg)
{
  __shared__ float sW1[160], sb1[32], sg1[32], sB1[32];
  __shared__ float sW2[128*33], sb2[128], sg2[128], sB2[128];
  __shared__ float h1[32], spt[8];
  __shared__ int lst[CAP], srt[10];
  const int tid = threadIdx.x;   // 128
  for (int i=tid;i<160;i+=128) sW1[i]=prm[O_V1W+i];
  if (tid<32){ sb1[tid]=prm[O_V1B+tid]; sg1[tid]=prm[O_V1G+tid]; sB1[tid]=prm[O_V1BT+tid]; }
  for (int i=tid;i<4096;i+=128){ sW2[(i/32)*33 + (i%32)] = prm[O_V2W+i]; }
  sb2[tid]=prm[O_V2B+tid]; sg2[tid]=prm[O_V2G+tid]; sB2[tid]=prm[O_V2BT+tid];
  __syncthreads();
  const int n = (int)counters[0];
  for (int c=0;c<8;++c){
    const int gid = blockIdx.x*8+c;
    if (gid >= n) break;
    const int total = (int)scnt[gid];
    const int cc = total<CAP?total:CAP;
    const int np = total<10?total:10;
    if (tid < cc) lst[tid] = slots[gid*CAP+tid];
    __syncthreads();
    if (tid < cc){
      const int my = lst[tid]; int r=0;
      for (int j=0;j<cc;++j) r += (lst[j] < my) ? 1 : 0;   // stable-sort rank by input index
      if (r < 10) srt[r] = my;
    }
    __syncthreads();
    float vmax = 0.f;
    for (int r=0;r<np;++r){
      const int pi = srt[r];
      if (tid<5) spt[tid] = pts[(size_t)pi*5+tid];
      __syncthreads();
      if (tid<32){
        float s = sb1[tid];
        #pragma unroll
        for (int j=0;j<5;++j) s += sW1[tid*5+j]*spt[j];
        s = s*sg1[tid]+sB1[tid];
        h1[tid] = s>0.f?s:0.f;
      }
      __syncthreads();
      float s = sb2[tid];
      #pragma unroll
      for (int j=0;j<32;++j) s += sW2[tid*33+j]*h1[j];
      s = s*sg2[tid]+sB2[tid];
      s = s>0.f?s:0.f;
      vmax = fmaxf(vmax, s);
      __syncthreads();
    }
    if (np<10) vmax = fmaxf(vmax, z128[tid]);   // phantom zero-point rows
    F0c[(size_t)gid*128+tid] = __float2bfloat16(vmax);
    if (tid==0){
      const int cell = keptList[gid];
      const int ix=cell/2000, iy=(cell/20)%100, iz=cell%20;
      const int didx = (iz*GYC+iy)*GXC+ix;
      m0[didx]=1; list0[gid]=didx;
      atomicAdd(cdbg+3,1u);
    }
    __syncthreads();
  }
}

// ---------- occupancy pooling ----------
__global__ void k_pool(const unsigned char* __restrict__ mIn, unsigned char* __restrict__ mOut,
                       int* __restrict__ listOut, unsigned* __restrict__ counter,
                       int IZ,int IY,int IX,int OZ,int OY,int OX)
{
  const int s = blockIdx.x*256+threadIdx.x;
  if (s >= OZ*OY*OX) return;
  const int ox=s%OX, oy=(s/OX)%OY, oz=s/(OX*OY);
  bool any=false;
  for (int dz=0;dz<3;++dz){ int nz=oz*2+dz-1; if(nz<0||nz>=IZ)continue;
    for (int dy=0;dy<3;++dy){ int ny=oy*2+dy-1; if(ny<0||ny>=IY)continue;
      for (int dx=0;dx<3;++dx){ int nx=ox*2+dx-1; if(nx<0||nx>=IX)continue;
        any = any || (mIn[(nz*IY+ny)*IX+nx] != 0);
      }}}
  if (any){ mOut[s]=1; unsigned p=atomicAdd(counter,1u); listOut[p]=s; }
}

// ---------- weight re-layout: OIDHW f32 -> [(k*(I/8)+i8)][o][8] f32 ----------
__global__ void k_wt(const float* __restrict__ src, float* __restrict__ dst,
                     int O, int I, int K)
{
  const int idx = blockIdx.x*256+threadIdx.x;
  if (idx >= O*I*K) return;
  const int j = idx & 7;
  const int o = (idx >> 3) % O;
  const int rest = idx / (8*O);
  const int i8 = rest % (I/8);
  const int k = rest / (I/8);
  dst[idx] = src[((size_t)o*I + i8*8 + j)*K + k];
}

// ---------- masked 3D conv: INMODE 0=dense,1=compact-via-map; OUTMODE 0=dense,2=BEV ----------
template<int CIN, int COUT, int STRIDE, int SITES, int INMODE, int OUTMODE>
__global__ __launch_bounds__(256) void k_conv3(
    const bf16* __restrict__ inP, bf16* __restrict__ out,
    const float* __restrict__ Wt,
    const float* __restrict__ gam, const float* __restrict__ bet,
    const int* __restrict__ list, const unsigned* __restrict__ nPtr,
    const int* __restrict__ map,
    int IZ, int IY, int IX, int OY, int OX)
{
  extern __shared__ char smem[];
  bf16* act = (bf16*)smem;   // [SITES][27][CIN]
  const int n = (int)(*nPtr);
  const int base = (int)blockIdx.x * SITES;
  if (base >= n) return;
  const int nval = (SITES < n-base) ? SITES : (n-base);
  const int tid = threadIdx.x;
  constexpr int NVS = 27*CIN/8;
  for (int s=0;s<nval;++s){
    const int site = list[base+s];
    const int ox = site % OX;
    const int oy = (site/OX) % OY;
    const int oz = site/(OX*OY);
    for (int v=tid; v<NVS; v+=256){
      const int k = v/(CIN/8);
      const int cv = v%(CIN/8);
      const int dz = k/9, dy=(k/3)%3, dx=k%3;
      const int nz = oz*STRIDE+dz-1, ny=oy*STRIDE+dy-1, nx=ox*STRIDE+dx-1;
      uint4 val = make_uint4(0u,0u,0u,0u);
      if (nz>=0 && nz<IZ && ny>=0 && ny<IY && nx>=0 && nx<IX){
        const int nd = (nz*IY+ny)*IX+nx;
        if constexpr (INMODE==1){
          const int mi = map[nd];
          if (mi >= 0) val = *(const uint4*)(inP + (size_t)mi*CIN + cv*8);
        } else {
          val = *(const uint4*)(inP + (size_t)nd*CIN + cv*8);
        }
      }
      *(uint4*)(act + (size_t)(s*27+k)*CIN + cv*8) = val;
    }
  }
  __syncthreads();
  constexpr int WPS = 256/COUT;
  const int o = tid % COUT;
  const int sl = tid / COUT;
  const float gs = gam[o];
  const float bs = bet[o];
  for (int s=sl; s<nval; s+=WPS){
    const bf16* a = act + (size_t)s*27*CIN;
    float acc = 0.f;
    for (int grp=0; grp<27*CIN/8; ++grp){
      float av[8]; loadA8(a + grp*8, av);
      float wv[8]; loadA8f(Wt + ((size_t)grp*COUT + o)*8, wv);
      #pragma unroll
      for (int j=0;j<8;++j) acc += av[j]*wv[j];
    }
    float vv = acc*gs + bs; vv = vv>0.f?vv:0.f;
    size_t oidx;
    if constexpr (OUTMODE==2){
      const int site = list[base+s];
      const int ox2 = site%OX, oy2=(site/OX)%OY, oz2=site/(OX*OY);
      oidx = ((size_t)(oy2*OX+ox2)*5 + oz2)*COUT + o;   // BEV [y][x][z*COUT+c]
    } else {
      oidx = (size_t)list[base+s]*COUT + o;
    }
    out[oidx] = __float2bfloat16(vv);
  }
}

// ---------- dense 2D BEV conv + bias + BN + ReLU; FINAL writes f32 (C,H,W) ----------
template<typename TIN, int CIN, int COUT, bool FINAL>
__global__ __launch_bounds__(256) void k_conv2(
    const TIN* __restrict__ in, float* __restrict__ out,
    const float* __restrict__ Wt,
    const float* __restrict__ bias, const float* __restrict__ gam, const float* __restrict__ bet)
{
  extern __shared__ char smem[];
  TIN* patch = (TIN*)smem;   // [3][7][CIN]
  const int tid = threadIdx.x;
  const int y  = (int)blockIdx.x/5;
  const int x0 = ((int)blockIdx.x%5)*5;
  constexpr int VPER = 16/(int)sizeof(TIN);
  constexpr int NVS = 21*CIN/VPER;
  for (int v=tid; v<NVS; v+=256){
    const int rc = v/(CIN/VPER);
    const int cv = v%(CIN/VPER);
    const int r = rc/7, c = rc%7;
    const int ry = y-1+r, cx = x0-1+c;
    uint4 val = make_uint4(0u,0u,0u,0u);
    if (ry>=0 && ry<25 && cx>=0 && cx<25)
      val = *(const uint4*)(in + (size_t)(ry*25+cx)*CIN + cv*VPER);
    *(uint4*)(patch + (size_t)rc*CIN + cv*VPER) = val;
  }
  __syncthreads();
  const int o = (int)blockIdx.y*256 + tid;
  float accs[5] = {0.f,0.f,0.f,0.f,0.f};
  for (int kk=0; kk<9; ++kk){
    const int ky=kk/3, kx=kk%3;
    for (int ci8=0; ci8<CIN/8; ++ci8){
      float wv[8]; loadA8f(Wt + ((size_t)(kk*(CIN/8)+ci8)*COUT + o)*8, wv);
      #pragma unroll
      for (int s=0;s<5;++s){
        float av[8];
        if constexpr (sizeof(TIN)==2) loadA8((const bf16*)(patch + (size_t)(ky*7+kx+s)*CIN + ci8*8), av);
        else loadA8f((const float*)(patch + (size_t)(ky*7+kx+s)*CIN + ci8*8), av);
        #pragma unroll
        for (int j=0;j<8;++j) accs[s] += av[j]*wv[j];
      }
    }
  }
  const float bi = bias[o];
  const float gs = gam[o];
  const float bs = bet[o];
  #pragma unroll
  for (int s=0;s<5;++s){
    float vv = (accs[s]+bi)*gs + bs; vv = vv>0.f?vv:0.f;
    const int x = x0+s;
    if constexpr (FINAL)
      out[((size_t)o*25 + y)*25 + x] = vv;           // f32 output (C,H,W)
    else
      out[(size_t)(y*25+x)*COUT + o] = vv;           // f32 site-major for next conv
  }
}

// ---------- full keptList/map/list0 audit ----------
__global__ __launch_bounds__(1024) void k_audit(const int* __restrict__ keptList,
    const int* __restrict__ map, const unsigned* __restrict__ cnt,
    const int* __restrict__ list0, const unsigned* __restrict__ nPtr,
    unsigned* __restrict__ ctr)
{
  const int n = (int)(*nPtr);
  for (int g = threadIdx.x; g < n; g += 1024){
    const int cell = keptList[g];
    unsigned bits = 0;
    if (g > 0 && keptList[g-1] >= cell) bits |= 1u;
    if (cell < 0 || cell >= NCELL) bits |= 2u;
    else {
      const int ix=cell/2000, iy=(cell/20)%100, iz=cell%20;
      const int didx=(iz*100+iy)*100+ix;
      if (map[didx] != g) bits |= 4u;
      if (cnt[cell] == 0u) bits |= 8u;
      if (list0[g] != didx) bits |= 16u;
    }
    if (bits) atomicOr(&ctr[40], bits);
  }
}

// ---------- wide-coverage stage goldens ----------
struct G6 { const float* w[6]; };
__global__ void k_gold2(
    const float* __restrict__ pts,
    const float* __restrict__ prm, const float* __restrict__ z128,
    const unsigned* __restrict__ scnt, const int* __restrict__ slots,
    const bf16* __restrict__ F0c, const bf16* __restrict__ F1,
    const bf16* __restrict__ F2, const bf16* __restrict__ F3,
    const bf16* __restrict__ F4, const float* __restrict__ bev1,
    const float* __restrict__ outp,
    const int* __restrict__ list0, const int* __restrict__ list1,
    const int* __restrict__ list2, const int* __restrict__ map,
    G6 g6, unsigned* __restrict__ ctr)
{
  const int t = threadIdx.x;
  const unsigned n0 = ctr[0], n1 = ctr[1], n2 = ctr[2];
  if (n0 == 0u || n1 == 0u || n2 == 0u) return;
  auto rep = [&](int stage, float golden, float pipe){
    float rel = fabsf(golden-pipe)/(1.0f+fabsf(golden));
    if (rel > 0.02f) atomicAdd(&ctr[22+stage], 1u);
  };
  if (t < 64){
    const int g = (t*937) % (int)n0;
    const int didx = list0[g];
    const int ix=didx%100, iy=(didx/100)%100, iz=didx/10000;
    const int o = (g*7)%64;
    float acc = 0.f;
    for (int k=0;k<27;++k){
      const int dz=k/9, dy=(k/3)%3, dx=k%3;
      const int nz=iz+dz-1, ny=iy+dy-1, nx=ix+dx-1;
      if (nz<0||nz>=20||ny<0||ny>=100||nx<0||nx>=100) continue;
      const int mi = map[(nz*100+ny)*100+nx];
      if (mi<0) continue;
      for (int i=0;i<128;++i)
        acc += g6.w[0][((size_t)o*128+i)*27+k]*b2f(F0c[(size_t)mi*128+i]);
    }
    float v = acc*prm[O_SP1G+o]+prm[O_SP1B+o]; v=v>0.f?v:0.f;
    rep(1, v, b2f(F1[(size_t)didx*64+o]));
  } else if (t < 96){
    const int k = t-64;
    const int s = list1[((unsigned)k*331u)%n1];
    const int ox=s%50, oy=(s/50)%50, oz=s/2500;
    const int o=(k*11)%128;
    float acc=0.f;
    for (int kk=0;kk<27;++kk){
      const int dz=kk/9, dy=(kk/3)%3, dx=kk%3;
      const int nz=2*oz+dz-1, ny=2*oy+dy-1, nx=2*ox+dx-1;
      if (nz<0||nz>=20||ny<0||ny>=100||nx<0||nx>=100) continue;
      const size_t nd=(size_t)(nz*100+ny)*100+nx;
      for (int i=0;i<64;++i)
        acc += g6.w[1][((size_t)o*64+i)*27+kk]*b2f(F1[nd*64+i]);
    }
    float v=acc*prm[O_SP2G+o]+prm[O_SP2B+o]; v=v>0.f?v:0.f;
    rep(2, v, b2f(F2[(size_t)s*128+o]));
  } else if (t < 128){
    const int k=t-96;
    const int s = list1[((unsigned)k*317u)%n1];
    const int ox=s%50, oy=(s/50)%50, oz=s/2500;
    const int o=(k*13)%128;
    float acc=0.f;
    for (int kk=0;kk<27;++kk){
      const int dz=kk/9, dy=(kk/3)%3, dx=kk%3;
      const int nz=oz+dz-1, ny=oy+dy-1, nx=ox+dx-1;
      if (nz<0||nz>=10||ny<0||ny>=50||nx<0||nx>=50) continue;
      const size_t nd=(size_t)(nz*50+ny)*50+nx;
      for (int i=0;i<128;++i)
        acc += g6.w[2][((size_t)o*128+i)*27+kk]*b2f(F2[nd*128+i]);
    }
    float v=acc*prm[O_SP3G+o]+prm[O_SP3B+o]; v=v>0.f?v:0.f;
    rep(3, v, b2f(F3[(size_t)s*128+o]));
  } else if (t < 160){
    const int k=t-128;
    const int s = list2[((unsigned)k*43u)%n2];
    const int ox=s%25, oy=(s/25)%25, oz=s/625;
    const int o=(k*17)%256;
    float acc=0.f;
    for (int kk=0;kk<27;++kk){
      const int dz=kk/9, dy=(kk/3)%3, dx=kk%3;
      const int nz=2*oz+dz-1, ny=2*oy+dy-1, nx=2*ox+dx-1;
      if (nz<0||nz>=10||ny<0||ny>=50||nx<0||nx>=50) continue;
      const size_t nd=(size_t)(nz*50+ny)*50+nx;
      for (int i=0;i<128;++i)
        acc += g6.w[3][((size_t)o*128+i)*27+kk]*b2f(F3[nd*128+i]);
    }
    float v=acc*prm[O_SP4G+o]+prm[O_SP4B+o]; v=v>0.f?v:0.f;
    rep(4, v, b2f(F4[((size_t)(oy*25+ox)*5+oz)*256+o]));
  } else if (t < 176){
    const int k=t-160;
    const int y=(k*11)%25, x=(k*3)%13;
    const int o=(k*29)%512;
    float acc=0.f;
    for (int kk=0;kk<9;++kk){
      const int ky=kk/3, kx=kk%3;
      const int ry=y-1+ky, cx=x-1+kx;
      if (ry<0||ry>=25||cx<0||cx>=25) continue;
      for (int ci=0;ci<1280;++ci)
        acc += g6.w[4][((size_t)o*1280+ci)*9+kk]*b2f(F4[(size_t)(ry*25+cx)*1280+ci]);
    }
    float v=(acc+prm[O_BV1B+o])*prm[O_BV1G+o]+prm[O_BV1BT+o]; v=v>0.f?v:0.f;
    rep(5, v, bev1[(size_t)(y*25+x)*512+o]);
  } else if (t < 192){
    const int k=t-176;
    const int y=(k*7)%25, x=(k*3+1)%13;
    const int c=(k*31)%256;
    float acc=0.f;
    for (int kk=0;kk<9;++kk){
      const int ky=kk/3, kx=kk%3;
      const int ry=y-1+ky, cx=x-1+kx;
      if (ry<0||ry>=25||cx<0||cx>=25) continue;
      for (int ci=0;ci<512;++ci)
        acc += g6.w[5][((size_t)c*512+ci)*9+kk]*bev1[(size_t)(ry*25+cx)*512+ci];
    }
    float v=(acc+prm[O_BV2B+c])*prm[O_BV2G+c]+prm[O_BV2BT+c]; v=v>0.f?v:0.f;
    rep(6, v, outp[((size_t)c*25+y)*25+x]);
  } else if (t < 224){
    const int k=t-192;
    const int gid = (k*1877) % (int)n0;
    const int o = (k*19)%128;
    const int total = (int)scnt[gid];
    const int cc = total<CAP?total:CAP;
    const int np = total<10?total:10;
    int idx[CAP];
    for (int j=0;j<cc;++j) idx[j]=slots[gid*CAP+j];
    for (int a=0;a<cc;++a) for (int b=a+1;b<cc;++b)
      if (idx[b]<idx[a]){ int tmp=idx[a]; idx[a]=idx[b]; idx[b]=tmp; }
    float best = 0.f;
    float h1[32];
    for (int r=0;r<np;++r){
      float pt[5];
      for (int q=0;q<5;++q) pt[q]=pts[(size_t)idx[r]*5+q];
      for (int j=0;j<32;++j){
        float s = prm[O_V1B+j];
        for (int q=0;q<5;++q) s += prm[O_V1W+j*5+q]*pt[q];
        s = s*prm[O_V1G+j]+prm[O_V1BT+j];
        h1[j]=s>0.f?s:0.f;
      }
      float s = prm[O_V2B+o];
      for (int j=0;j<32;++j) s += prm[O_V2W+o*32+j]*h1[j];
      s = s*prm[O_V2G+o]+prm[O_V2BT+o];
      s = s>0.f?s:0.f;
      best = fmaxf(best, s);
    }
    if (np<10) best = fmaxf(best, z128[o]);
    rep(0, best, b2f(F0c[(size_t)gid*128+o]));
  }
}

// ---------- visible f32 beacon: fires ONLY on failure ----------
__global__ void k_beacon(const unsigned* __restrict__ ctr, int N, float* __restrict__ out)
{
  if (threadIdx.x != 0) return;
  const unsigned n0=ctr[0], n1=ctr[1], n2=ctr[2], nv=ctr[3], pts=ctr[4];
  int E=0; unsigned m=0;
  if      (pts > (unsigned)N || pts+1000u < (unsigned)N){ E=12; m=pts>>12; }
  else if (n0 != 60000u)               { E=13; m=n0>>9; }
  else if (nv != n0)                   { E=14; m=nv>>9; }
  else if (n1 < 9000u || n1 > 13000u)  { E=15; m=n1>>7; }
  else if (n2 < 1100u || n2 > 1700u)   { E=16; m=n2>>4; }
  else if (ctr[40])                    { E=18; m=ctr[40]&255u; }
  else {
    for (int s=0;s<=6;++s)
      if (ctr[22+s]){ E=22+s; m=(ctr[22+s]<255u)?ctr[22+s]:255u; break; }
  }
  if (E) out[0] = ldexpf(1.0f + (float)(m & 255u)/256.0f, E);
}

// ---------- launch ----------
extern "C" void kernel_launch(void* const* d_in, const int* in_sizes, int n_in,
                              void* d_out, int out_size, void* d_ws, size_t ws_size,
                              hipStream_t stream)
{
  (void)n_in; (void)out_size; (void)ws_size;
  const int N = in_sizes[0] / 5;

  char* p = (char*)d_ws;
  size_t off = 0;
  auto carve = [&](size_t bytes)->char*{
    char* r = p + off;
    off += (bytes + 255) & ~(size_t)255;
    return r;
  };
  // ---- zero region ----
  unsigned*      counters = (unsigned*)     carve(256);
  unsigned*      cnt      = (unsigned*)     carve((size_t)NCELL*4);
  unsigned*      scnt     = (unsigned*)     carve((size_t)MAXVX*4);
  unsigned char* m0       = (unsigned char*)carve(NCELL);
  unsigned char* m1       = (unsigned char*)carve(25000);
  unsigned char* m2       = (unsigned char*)carve(3125);
  bf16*  F0c   = (bf16*) carve((size_t)MAXVX*128*2);
  bf16*  F1    = (bf16*) carve((size_t)NCELL*64*2);     // dense (20,100,100,64)
  bf16*  F2    = (bf16*) carve((size_t)25000*128*2);
  bf16*  F3    = (bf16*) carve((size_t)25000*128*2);
  bf16*  F4    = (bf16*) carve((size_t)3125*256*2);
  float* bev1  = (float*)carve((size_t)625*512*4);
  const size_t zero_total = off;
  // ---- non-zero ----
  int*   map      = (int*)  carve((size_t)NCELL*4);      // 0xFF
  int*   keptList = (int*)  carve((size_t)MAXVX*4);
  int*   list0    = (int*)  carve((size_t)MAXVX*4);
  int*   list1    = (int*)  carve((size_t)25000*4);
  int*   list2    = (int*)  carve((size_t)3125*4);
  int*   slots    = (int*)  carve((size_t)MAXVX*CAP*4);
  float* prm      = (float*)carve(8192*4);
  float* z128     = (float*)carve(512);
  float* Wt1      = (float*)carve((size_t)27*128*64*4);
  float* Wt2      = (float*)carve((size_t)27*64*128*4);
  float* Wt3      = (float*)carve((size_t)27*128*128*4);
  float* Wt4      = (float*)carve((size_t)27*128*256*4);
  float* WtB1     = (float*)carve((size_t)9*1280*512*4);
  float* WtB2     = (float*)carve((size_t)9*512*256*4);

  hipMemsetAsync(d_ws, 0, zero_total, stream);
  hipMemsetAsync(map, 0xFF, (size_t)NCELL*4, stream);

  P22 ps;
  const int prmIdx[22] = {1,2,3,4,5,6,7,8, 10,11, 13,14, 16,17, 19,20, 22,23,24, 26,27,28};
  for (int e=0;e<22;++e) ps.p[e] = (const float*)d_in[prmIdx[e]];
  k_params<<<1,256,0,stream>>>(ps, prm);
  k_z128<<<1,128,0,stream>>>(prm, z128);
  k_wt<<<cdiv(64*128*27,256),256,0,stream>>>((const float*)d_in[9],  Wt1, 64,128,27);
  k_wt<<<cdiv(128*64*27,256),256,0,stream>>>((const float*)d_in[12], Wt2, 128,64,27);
  k_wt<<<cdiv(128*128*27,256),256,0,stream>>>((const float*)d_in[15], Wt3, 128,128,27);
  k_wt<<<cdiv(256*128*27,256),256,0,stream>>>((const float*)d_in[18], Wt4, 256,128,27);
  k_wt<<<cdiv(512*1280*9,256),256,0,stream>>>((const float*)d_in[21], WtB1, 512,1280,9);
  k_wt<<<cdiv(256*512*9,256),256,0,stream>>>((const float*)d_in[25], WtB2, 256,512,9);

  const float* pts = (const float*)d_in[0];
  k_points<<<cdiv(N,256),256,0,stream>>>(pts, N, cnt, counters);
  k_rank<<<1,1024,0,stream>>>(cnt, keptList, map, counters);
  k_points2<<<cdiv(N,256),256,0,stream>>>(pts, N, map, scnt, slots);
  k_vfe<<<cdiv(MAXVX,8),128,0,stream>>>(pts, prm, scnt, slots, keptList, counters,
                                        z128, F0c, m0, list0, counters);

  k_pool<<<cdiv(25000,256),256,0,stream>>>(m0, m1, list1, counters+1, 20,100,100, 10,50,50);
  k_pool<<<cdiv(3125,256),256,0,stream>>>(m1, m2, list2, counters+2, 10,50,50, 5,25,25);

  k_conv3<128,64,1,8,1,0><<<cdiv(MAXVX,8),256,8*27*128*2,stream>>>(
      F0c, F1, Wt1, prm+O_SP1G, prm+O_SP1B, list0, counters+0, map, 20,100,100, 100,100);
  k_conv3<64,128,2,8,0,0><<<cdiv(25000,8),256,8*27*64*2,stream>>>(
      F1, F2, Wt2, prm+O_SP2G, prm+O_SP2B, list1, counters+1, map, 20,100,100, 50,50);
  k_conv3<128,128,1,8,0,0><<<cdiv(25000,8),256,8*27*128*2,stream>>>(
      F2, F3, Wt3, prm+O_SP3G, prm+O_SP3B, list1, counters+1, map, 10,50,50, 50,50);
  k_conv3<128,256,2,8,0,2><<<cdiv(3125,8),256,8*27*128*2,stream>>>(
      F3, F4, Wt4, prm+O_SP4G, prm+O_SP4B, list2, counters+2, map, 10,50,50, 25,25);

  k_conv2<bf16,1280,512,false><<<dim3(125,2),256,21*1280*2,stream>>>(
      F4, bev1, WtB1, prm+O_BV1B, prm+O_BV1G, prm+O_BV1BT);
  k_conv2<float,512,256,true><<<dim3(125,1),256,21*512*4,stream>>>(
      bev1, (float*)d_out, WtB2, prm+O_BV2B, prm+O_BV2G, prm+O_BV2BT);

  // diagnostics (visible f32 beacon fires only on failure)
  k_audit<<<1,1024,0,stream>>>(keptList, map, cnt, list0, counters, counters);
  G6 g6;
  g6.w[0]=(const float*)d_in[9];  g6.w[1]=(const float*)d_in[12];
  g6.w[2]=(const float*)d_in[15]; g6.w[3]=(const float*)d_in[18];
  g6.w[4]=(const float*)d_in[21]; g6.w[5]=(const float*)d_in[25];
  k_gold2<<<1,256,0,stream>>>(pts, prm, z128, scnt, slots,
                              F0c, F1, F2, F3, F4, bev1, (const float*)d_out,
                              list0, list1, list2, map, g6, counters);
  k_beacon<<<1,64,0,stream>>>(counters, N, (float*)d_out);
}

// Round 11
// 1436.680 us; speedup vs baseline: 3.7768x; 3.7768x over previous
//
#include <hip/hip_runtime.h>
#include <hip/hip_bf16.h>
#include <cstdint>
#include <cstddef>

typedef __hip_bfloat16 bf16;
typedef short short8 __attribute__((ext_vector_type(8)));
typedef float f32x4 __attribute__((ext_vector_type(4)));

#define GXC 100
#define GYC 100
#define GZC 20
#define NCELL (GXC*GYC*GZC)
#define MAXVX 60000
#define CAP 12

static inline int cdiv(int a, int b){ return (a+b-1)/b; }

__device__ __forceinline__ float b2f(bf16 v){ return __bfloat162float(v); }
__device__ __forceinline__ void unpk2(unsigned u, float& lo, float& hi){
  union { unsigned q; float f; } a, b;
  a.q = u << 16; b.q = u & 0xFFFF0000u;
  lo = a.f; hi = b.f;
}
__device__ __forceinline__ void loadA8(const bf16* p, float* av){
  const uint4 u = *(const uint4*)p;
  unpk2(u.x, av[0], av[1]); unpk2(u.y, av[2], av[3]);
  unpk2(u.z, av[4], av[5]); unpk2(u.w, av[6], av[7]);
}
__device__ __forceinline__ void loadA8f(const float* p, float* av){
  const float4 u0 = *(const float4*)p;
  const float4 u1 = *((const float4*)p + 1);
  av[0]=u0.x; av[1]=u0.y; av[2]=u0.z; av[3]=u0.w;
  av[4]=u1.x; av[5]=u1.y; av[6]=u1.z; av[7]=u1.w;
}

// ---------- params gather ----------
struct P22 { const float* p[22]; };
__global__ void k_params(P22 ps, float* __restrict__ prm)
{
  const int ns[22] = {160,32,32,32,4096,128,128,128,64,64,128,128,128,128,256,256,512,512,512,256,256,256};
  int off = 0;
  for (int e=0;e<22;++e){
    const float* s = ps.p[e];
    const int n = ns[e];
    for (int i=threadIdx.x;i<n;i+=256) prm[off+i] = s[i];
    off += n;
  }
}
#define O_V1W 0
#define O_V1B 160
#define O_V1G 192
#define O_V1BT 224
#define O_V2W 256
#define O_V2B 4352
#define O_V2G 4480
#define O_V2BT 4608
#define O_SP1G 4736
#define O_SP1B 4800
#define O_SP2G 4864
#define O_SP2B 4992
#define O_SP3G 5120
#define O_SP3B 5248
#define O_SP4G 5376
#define O_SP4B 5632
#define O_BV1B 5888
#define O_BV1G 6400
#define O_BV1BT 6912
#define O_BV2B 7424
#define O_BV2G 7680
#define O_BV2BT 7936

// ---------- voxelize pass 1 ----------
__global__ void k_points(const float* __restrict__ pts, int N, unsigned* __restrict__ cnt)
{
  const int i = blockIdx.x*256 + threadIdx.x;
  if (i >= N) return;
  float x = pts[(size_t)i*5+0];
  float y = pts[(size_t)i*5+1];
  float z = pts[(size_t)i*5+2];
  float qx = (x - (-51.2f)) / 1.024f;
  float qy = (y - (-51.2f)) / 1.024f;
  float qz = (z - (-5.0f))  / 0.4f;
  int gx=(int)floorf(qx), gy=(int)floorf(qy), gz=(int)floorf(qz);
  if (x == 0.0f) return;
  if (gx<0||gx>=GXC||gy<0||gy>=GYC||gz<0||gz>=GZC) return;
  atomicAdd(&cnt[gx*(GYC*GZC) + gy*GZC + gz], 1u);
}

// ---------- rank occupied cells (cell-id order), first MAXVX kept ----------
__global__ __launch_bounds__(1024) void k_rank(const unsigned* __restrict__ cnt,
                                               int* __restrict__ keptList,
                                               int* __restrict__ map,
                                               unsigned* __restrict__ counters)
{
  __shared__ int wsum[16];
  __shared__ int sbase;
  const int tid = threadIdx.x;
  const int lane = tid & 63;
  const int w = tid >> 6;
  if (tid==0) sbase = 0;
  __syncthreads();
  for (int c0=0; c0<NCELL; c0+=1024){
    const int cell = c0 + tid;
    const int fl = (cell<NCELL && cnt[cell]>0u) ? 1 : 0;
    const unsigned long long m = __ballot(fl);
    const int wp = __popcll(m & ((1ull<<lane)-1ull));
    if (lane==0) wsum[w] = __popcll(m);
    __syncthreads();
    int wbase = 0;
    #pragma unroll
    for (int j=0;j<16;++j) wbase += (j<w) ? wsum[j] : 0;
    const int rank = sbase + wbase + wp;
    if (fl && rank < MAXVX){
      keptList[rank] = cell;
      const int ix=cell/2000, iy=(cell/20)%100, iz=cell%20;
      map[(iz*GYC+iy)*GXC+ix] = rank;
    }
    __syncthreads();
    if (tid==0){ int tot=0; for (int j=0;j<16;++j) tot+=wsum[j]; sbase+=tot; }
    __syncthreads();
  }
  if (tid==0) counters[0] = (unsigned)(sbase < MAXVX ? sbase : MAXVX);
}

// ---------- voxelize pass 2 ----------
__global__ void k_points2(const float* __restrict__ pts, int N,
                          const int* __restrict__ map,
                          unsigned* __restrict__ scnt, int* __restrict__ slots)
{
  const int i = blockIdx.x*256 + threadIdx.x;
  if (i >= N) return;
  float x = pts[(size_t)i*5+0];
  float y = pts[(size_t)i*5+1];
  float z = pts[(size_t)i*5+2];
  float qx = (x - (-51.2f)) / 1.024f;
  float qy = (y - (-51.2f)) / 1.024f;
  float qz = (z - (-5.0f))  / 0.4f;
  int gx=(int)floorf(qx), gy=(int)floorf(qy), gz=(int)floorf(qz);
  if (x == 0.0f) return;
  if (gx<0||gx>=GXC||gy<0||gy>=GYC||gz<0||gz>=GZC) return;
  const int didx = (gz*GYC+gy)*GXC+gx;
  const int r = map[didx];
  if (r < 0) return;
  unsigned pos = atomicAdd(&scnt[r], 1u);
  if (pos < CAP) slots[r*CAP + pos] = i;
}

// ---------- z128 ----------
__global__ void k_z128(const float* __restrict__ prm, float* __restrict__ z128)
{
  __shared__ float h1[32];
  const int tid = threadIdx.x;   // 128
  if (tid<32){ float s = prm[O_V1B+tid]*prm[O_V1G+tid]+prm[O_V1BT+tid]; h1[tid]=s>0.f?s:0.f; }
  __syncthreads();
  float s = prm[O_V2B+tid];
  for (int j=0;j<32;++j) s += prm[O_V2W+tid*32+j]*h1[j];
  s = s*prm[O_V2G+tid] + prm[O_V2BT+tid];
  z128[tid] = s>0.f?s:0.f;
}

// ---------- VFE: wave-per-voxel, barrier-free hot loop ----------
#define VPW 16
__global__ __launch_bounds__(256) void k_vfe(
  const float* __restrict__ pts, const float* __restrict__ prm,
  const unsigned* __restrict__ scnt, const int* __restrict__ slots,
  const int* __restrict__ keptList, const unsigned* __restrict__ counters,
  const float* __restrict__ z128,
  bf16* __restrict__ F0c, unsigned char* __restrict__ m0, int* __restrict__ list0)
{
  __shared__ float sW1[160], sb1[32], sg1[32], sB1[32];
  __shared__ float sW2[128*33];
  __shared__ float sb2[128], sg2[128], sB2[128], sz[128];
  __shared__ int sSrt[4][10];
  const int tid = threadIdx.x;
  for (int i=tid;i<160;i+=256) sW1[i]=prm[O_V1W+i];
  if (tid<32){ sb1[tid]=prm[O_V1B+tid]; sg1[tid]=prm[O_V1G+tid]; sB1[tid]=prm[O_V1BT+tid]; }
  for (int i=tid;i<4096;i+=256) sW2[(i>>5)*33 + (i&31)] = prm[O_V2W+i];
  if (tid<128){ sb2[tid]=prm[O_V2B+tid]; sg2[tid]=prm[O_V2G+tid]; sB2[tid]=prm[O_V2BT+tid]; sz[tid]=z128[tid]; }
  __syncthreads();
  const int wid = tid>>6, lane = tid&63;
  const int n = (int)counters[0];
  const int gid0 = ((int)blockIdx.x*4 + wid)*VPW;
  for (int v=0; v<VPW; ++v){
    const int gid = gid0 + v;
    if (gid >= n) break;                      // wave-uniform; no block barriers below
    const int total = (int)scnt[gid];
    const int cc = total<CAP?total:CAP;
    const int np = total<10?total:10;
    int myIdx = 0x7FFFFFFF;
    if (lane < cc) myIdx = slots[gid*CAP + lane];
    int rank = 0;
    for (int s=0;s<cc;++s){
      int vs = __shfl(myIdx, s);
      rank += (vs < myIdx) ? 1 : 0;           // distinct indices -> exact rank
    }
    if (lane < cc && rank < np) sSrt[wid][rank] = myIdx;   // wave-local LDS, in-wave ordered
    float vm0 = 0.f, vm1 = 0.f;
    for (int r=0;r<np;++r){
      const int pi = sSrt[wid][r];
      const float p0 = pts[(size_t)pi*5+0];
      const float p1 = pts[(size_t)pi*5+1];
      const float p2 = pts[(size_t)pi*5+2];
      const float p3 = pts[(size_t)pi*5+3];
      const float p4 = pts[(size_t)pi*5+4];
      float h = 0.f;
      if (lane < 32){
        float s = sb1[lane] + sW1[lane*5+0]*p0 + sW1[lane*5+1]*p1
                + sW1[lane*5+2]*p2 + sW1[lane*5+3]*p3 + sW1[lane*5+4]*p4;
        s = s*sg1[lane]+sB1[lane];
        h = s>0.f?s:0.f;
      }
      float s0 = sb2[lane], s1 = sb2[lane+64];
      #pragma unroll
      for (int j=0;j<32;++j){
        const float hj = __shfl(h, j);
        s0 += sW2[lane*33+j]*hj;
        s1 += sW2[(lane+64)*33+j]*hj;
      }
      s0 = s0*sg2[lane]+sB2[lane];    s0 = s0>0.f?s0:0.f;
      s1 = s1*sg2[lane+64]+sB2[lane+64]; s1 = s1>0.f?s1:0.f;
      vm0 = fmaxf(vm0, s0); vm1 = fmaxf(vm1, s1);
    }
    if (np<10){ vm0 = fmaxf(vm0, sz[lane]); vm1 = fmaxf(vm1, sz[lane+64]); }
    F0c[(size_t)gid*128 + lane]      = __float2bfloat16(vm0);
    F0c[(size_t)gid*128 + lane + 64] = __float2bfloat16(vm1);
    if (lane==0){
      const int cell = keptList[gid];
      const int ix=cell/2000, iy=(cell/20)%100, iz=cell%20;
      const int didx = (iz*GYC+iy)*GXC+ix;
      m0[didx]=1; list0[gid]=didx;
    }
  }
}

// ---------- occupancy pooling ----------
__global__ void k_pool(const unsigned char* __restrict__ mIn, unsigned char* __restrict__ mOut,
                       int* __restrict__ listOut, unsigned* __restrict__ counter,
                       int IZ,int IY,int IX,int OZ,int OY,int OX)
{
  const int s = blockIdx.x*256+threadIdx.x;
  if (s >= OZ*OY*OX) return;
  const int ox=s%OX, oy=(s/OX)%OY, oz=s/(OX*OY);
  bool any=false;
  for (int dz=0;dz<3;++dz){ int nz=oz*2+dz-1; if(nz<0||nz>=IZ)continue;
    for (int dy=0;dy<3;++dy){ int ny=oy*2+dy-1; if(ny<0||ny>=IY)continue;
      for (int dx=0;dx<3;++dx){ int nx=ox*2+dx-1; if(nx<0||nx>=IX)continue;
        any = any || (mIn[(nz*IY+ny)*IX+nx] != 0);
      }}}
  if (any){ mOut[s]=1; unsigned p=atomicAdd(counter,1u); listOut[p]=s; }
}

// ---------- MFMA weight re-layout: OIDHW f32 -> B-fragment bf16 [ct][ks][lane][8] ----------
__global__ void k_wtm(const float* __restrict__ src, bf16* __restrict__ dst, int COUT, int CIN)
{
  const int K = 27*CIN;
  const int idx = blockIdx.x*256+threadIdx.x;
  if (idx >= COUT*K) return;
  const int j = idx & 7;
  const int l = (idx >> 3) & 63;
  const int rest = idx >> 9;           // ct*KS + ks
  const int KS = K/32;
  const int ks = rest % KS;
  const int ct = rest / KS;
  const int o = ct*16 + (l & 15);
  const int k = ks*32 + ((l>>4)<<3) + j;
  const int kk = k / CIN;
  const int ci = k % CIN;
  dst[idx] = __float2bfloat16(src[((size_t)o*CIN + ci)*27 + kk]);
}

// ---------- BEV weight re-layout (unchanged, f32 grouped) ----------
__global__ void k_wt(const float* __restrict__ src, float* __restrict__ dst,
                     int O, int I, int K)
{
  const int idx = blockIdx.x*256+threadIdx.x;
  if (idx >= O*I*K) return;
  const int j = idx & 7;
  const int o = (idx >> 3) % O;
  const int rest = idx / (8*O);
  const int i8 = rest % (I/8);
  const int k = rest / (I/8);
  dst[idx] = src[((size_t)o*I + i8*8 + j)*K + k];
}

// ---------- MFMA implicit-GEMM masked 3D conv ----------
// INMODE 0: dense input grid (mi = flat idx). INMODE 1: compact via map.
// OUTMODE 0: dense by site. OUTMODE 2: BEV [y][x][z*COUT+c].
template<int CIN, int COUT, int STRIDE, int INMODE, int OUTMODE>
__global__ __launch_bounds__(256) void k_conv3m(
    const bf16* __restrict__ inP, bf16* __restrict__ out,
    const bf16* __restrict__ WtM,
    const float* __restrict__ gam, const float* __restrict__ bet,
    const int* __restrict__ list, const unsigned* __restrict__ nPtr,
    const int* __restrict__ map,
    int IZ, int IY, int IX, int OY, int OX)
{
  constexpr int K  = 27*CIN;
  constexpr int KS = K/32;
  constexpr int CS = CIN/32;
  __shared__ int sMi[16][27];
  __shared__ int sSite[16];
  const int n = (int)(*nPtr);
  const int base = (int)blockIdx.x * 16;
  if (base >= n) return;
  const int tid = threadIdx.x;
  for (int i=tid; i<16*27; i+=256){
    const int r = i/27, kk = i%27;
    int mi = -1, site = -1;
    if (base + r < n){
      site = list[base+r];
      const int ox = site % OX, oy = (site/OX)%OY, oz = site/(OX*OY);
      const int dz=kk/9, dy=(kk/3)%3, dx=kk%3;
      const int nz=oz*STRIDE+dz-1, ny=oy*STRIDE+dy-1, nx=ox*STRIDE+dx-1;
      if (nz>=0&&nz<IZ&&ny>=0&&ny<IY&&nx>=0&&nx<IX){
        const int nd=(nz*IY+ny)*IX+nx;
        mi = (INMODE==1) ? map[nd] : nd;
      }
    }
    if (kk==0) sSite[r] = site;
    sMi[r][kk] = mi;
  }
  __syncthreads();
  const int wid = tid>>6, lane = tid&63;
  const int ct = (int)blockIdx.y*4 + wid;
  const int row = lane & 15;
  const int koff = (lane>>4)<<3;
  const bf16* wptr = WtM + (((size_t)ct*KS)*64 + lane)*8;
  f32x4 acc = {0.f,0.f,0.f,0.f};
  for (int kk=0; kk<27; ++kk){
    const int mi = sMi[row][kk];
    const bf16* arow = inP + (size_t)(mi<0?0:mi)*CIN + koff;
    #pragma unroll
    for (int cs=0; cs<CS; ++cs){
      union { uint4 u; short8 v; } A;
      A.u = make_uint4(0u,0u,0u,0u);
      if (mi >= 0) A.u = *(const uint4*)(arow + cs*32);
      union { uint4 u; short8 v; } B;
      B.u = *(const uint4*)wptr;
      wptr += 64*8;
      acc = __builtin_amdgcn_mfma_f32_16x16x32_bf16(A.v, B.v, acc, 0, 0, 0);
    }
  }
  const int c = ct*16 + (lane & 15);
  const float gs = gam[c], bs = bet[c];
  #pragma unroll
  for (int j=0;j<4;++j){
    const int r = ((lane>>4)<<2) + j;
    const int site = sSite[r];
    if (site < 0) continue;
    float vv = acc[j]*gs + bs; vv = vv>0.f?vv:0.f;
    size_t oidx;
    if constexpr (OUTMODE==2){
      const int ox2=site%OX, oy2=(site/OX)%OY, oz2=site/(OX*OY);
      oidx = ((size_t)(oy2*OX+ox2)*5 + oz2)*COUT + c;
    } else {
      oidx = (size_t)site*COUT + c;
    }
    out[oidx] = __float2bfloat16(vv);
  }
}

// ---------- dense 2D BEV conv (unchanged; FINAL writes f32 CHW) ----------
template<typename TIN, int CIN, int COUT, bool FINAL>
__global__ __launch_bounds__(256) void k_conv2(
    const TIN* __restrict__ in, float* __restrict__ out,
    const float* __restrict__ Wt,
    const float* __restrict__ bias, const float* __restrict__ gam, const float* __restrict__ bet)
{
  extern __shared__ char smem[];
  TIN* patch = (TIN*)smem;   // [3][7][CIN]
  const int tid = threadIdx.x;
  const int y  = (int)blockIdx.x/5;
  const int x0 = ((int)blockIdx.x%5)*5;
  constexpr int VPER = 16/(int)sizeof(TIN);
  constexpr int NVS = 21*CIN/VPER;
  for (int v=tid; v<NVS; v+=256){
    const int rc = v/(CIN/VPER);
    const int cv = v%(CIN/VPER);
    const int r = rc/7, c = rc%7;
    const int ry = y-1+r, cx = x0-1+c;
    uint4 val = make_uint4(0u,0u,0u,0u);
    if (ry>=0 && ry<25 && cx>=0 && cx<25)
      val = *(const uint4*)(in + (size_t)(ry*25+cx)*CIN + cv*VPER);
    *(uint4*)(patch + (size_t)rc*CIN + cv*VPER) = val;
  }
  __syncthreads();
  const int o = (int)blockIdx.y*256 + tid;
  float accs[5] = {0.f,0.f,0.f,0.f,0.f};
  for (int kk=0; kk<9; ++kk){
    const int ky=kk/3, kx=kk%3;
    for (int ci8=0; ci8<CIN/8; ++ci8){
      float wv[8]; loadA8f(Wt + ((size_t)(kk*(CIN/8)+ci8)*COUT + o)*8, wv);
      #pragma unroll
      for (int s=0;s<5;++s){
        float av[8];
        if constexpr (sizeof(TIN)==2) loadA8((const bf16*)(patch + (size_t)(ky*7+kx+s)*CIN + ci8*8), av);
        else loadA8f((const float*)(patch + (size_t)(ky*7+kx+s)*CIN + ci8*8), av);
        #pragma unroll
        for (int j=0;j<8;++j) accs[s] += av[j]*wv[j];
      }
    }
  }
  const float bi = bias[o];
  const float gs = gam[o];
  const float bs = bet[o];
  #pragma unroll
  for (int s=0;s<5;++s){
    float vv = (accs[s]+bi)*gs + bs; vv = vv>0.f?vv:0.f;
    const int x = x0+s;
    if constexpr (FINAL)
      out[((size_t)o*25 + y)*25 + x] = vv;
    else
      out[(size_t)(y*25+x)*COUT + o] = vv;
  }
}

// ---------- launch ----------
extern "C" void kernel_launch(void* const* d_in, const int* in_sizes, int n_in,
                              void* d_out, int out_size, void* d_ws, size_t ws_size,
                              hipStream_t stream)
{
  (void)n_in; (void)out_size; (void)ws_size;
  const int N = in_sizes[0] / 5;

  char* p = (char*)d_ws;
  size_t off = 0;
  auto carve = [&](size_t bytes)->char*{
    char* r = p + off;
    off += (bytes + 255) & ~(size_t)255;
    return r;
  };
  // ---- zero region ----
  unsigned*      counters = (unsigned*)     carve(256);
  unsigned*      cnt      = (unsigned*)     carve((size_t)NCELL*4);
  unsigned*      scnt     = (unsigned*)     carve((size_t)MAXVX*4);
  unsigned char* m0       = (unsigned char*)carve(NCELL);
  unsigned char* m1       = (unsigned char*)carve(25000);
  unsigned char* m2       = (unsigned char*)carve(3125);
  bf16*  F0c   = (bf16*) carve((size_t)MAXVX*128*2);
  bf16*  F1    = (bf16*) carve((size_t)NCELL*64*2);     // dense (20,100,100,64)
  bf16*  F2    = (bf16*) carve((size_t)25000*128*2);
  bf16*  F3    = (bf16*) carve((size_t)25000*128*2);
  bf16*  F4    = (bf16*) carve((size_t)3125*256*2);
  float* bev1  = (float*)carve((size_t)625*512*4);
  const size_t zero_total = off;
  // ---- non-zero ----
  int*   map      = (int*)  carve((size_t)NCELL*4);      // 0xFF
  int*   keptList = (int*)  carve((size_t)MAXVX*4);
  int*   list0    = (int*)  carve((size_t)MAXVX*4);
  int*   list1    = (int*)  carve((size_t)25000*4);
  int*   list2    = (int*)  carve((size_t)3125*4);
  int*   slots    = (int*)  carve((size_t)MAXVX*CAP*4);
  float* prm      = (float*)carve(8192*4);
  float* z128     = (float*)carve(512);
  bf16*  Wm1      = (bf16*) carve((size_t)64*27*128*2);
  bf16*  Wm2      = (bf16*) carve((size_t)128*27*64*2);
  bf16*  Wm3      = (bf16*) carve((size_t)128*27*128*2);
  bf16*  Wm4      = (bf16*) carve((size_t)256*27*128*2);
  float* WtB1     = (float*)carve((size_t)9*1280*512*4);
  float* WtB2     = (float*)carve((size_t)9*512*256*4);

  hipMemsetAsync(d_ws, 0, zero_total, stream);
  hipMemsetAsync(map, 0xFF, (size_t)NCELL*4, stream);

  P22 ps;
  const int prmIdx[22] = {1,2,3,4,5,6,7,8, 10,11, 13,14, 16,17, 19,20, 22,23,24, 26,27,28};
  for (int e=0;e<22;++e) ps.p[e] = (const float*)d_in[prmIdx[e]];
  k_params<<<1,256,0,stream>>>(ps, prm);
  k_z128<<<1,128,0,stream>>>(prm, z128);
  k_wtm<<<cdiv(64*27*128,256),256,0,stream>>>((const float*)d_in[9],  Wm1, 64, 128);
  k_wtm<<<cdiv(128*27*64,256),256,0,stream>>>((const float*)d_in[12], Wm2, 128, 64);
  k_wtm<<<cdiv(128*27*128,256),256,0,stream>>>((const float*)d_in[15], Wm3, 128, 128);
  k_wtm<<<cdiv(256*27*128,256),256,0,stream>>>((const float*)d_in[18], Wm4, 256, 128);
  k_wt<<<cdiv(512*1280*9,256),256,0,stream>>>((const float*)d_in[21], WtB1, 512,1280,9);
  k_wt<<<cdiv(256*512*9,256),256,0,stream>>>((const float*)d_in[25], WtB2, 256,512,9);

  const float* pts = (const float*)d_in[0];
  k_points<<<cdiv(N,256),256,0,stream>>>(pts, N, cnt);
  k_rank<<<1,1024,0,stream>>>(cnt, keptList, map, counters);
  k_points2<<<cdiv(N,256),256,0,stream>>>(pts, N, map, scnt, slots);
  k_vfe<<<cdiv(MAXVX,4*VPW),256,0,stream>>>(pts, prm, scnt, slots, keptList, counters,
                                            z128, F0c, m0, list0);

  k_pool<<<cdiv(25000,256),256,0,stream>>>(m0, m1, list1, counters+1, 20,100,100, 10,50,50);
  k_pool<<<cdiv(3125,256),256,0,stream>>>(m1, m2, list2, counters+2, 10,50,50, 5,25,25);

  // sp1: compact-in via map -> dense F1.  M=60000, N=64, K=3456
  k_conv3m<128,64,1,1,0><<<dim3(cdiv(MAXVX,16),1),256,0,stream>>>(
      F0c, F1, Wm1, prm+O_SP1G, prm+O_SP1B, list0, counters+0, map, 20,100,100, 100,100);
  // sp2: dense F1 -> dense F2 (stride 2).  N=128, K=1728
  k_conv3m<64,128,2,0,0><<<dim3(cdiv(25000,16),2),256,0,stream>>>(
      F1, F2, Wm2, prm+O_SP2G, prm+O_SP2B, list1, counters+1, map, 20,100,100, 50,50);
  // sp3: dense F2 -> dense F3.  N=128, K=3456
  k_conv3m<128,128,1,0,0><<<dim3(cdiv(25000,16),2),256,0,stream>>>(
      F2, F3, Wm3, prm+O_SP3G, prm+O_SP3B, list1, counters+1, map, 10,50,50, 50,50);
  // sp4: dense F3 -> BEV F4 (stride 2).  N=256, K=3456
  k_conv3m<128,256,2,0,2><<<dim3(cdiv(3125,16),4),256,0,stream>>>(
      F3, F4, Wm4, prm+O_SP4G, prm+O_SP4B, list2, counters+2, map, 10,50,50, 25,25);

  k_conv2<bf16,1280,512,false><<<dim3(125,2),256,21*1280*2,stream>>>(
      F4, bev1, WtB1, prm+O_BV1B, prm+O_BV1G, prm+O_BV1BT);
  k_conv2<float,512,256,true><<<dim3(125,1),256,21*512*4,stream>>>(
      bev1, (float*)d_out, WtB2, prm+O_BV2B, prm+O_BV2G, prm+O_BV2BT);
}

// Round 12
// 905.887 us; speedup vs baseline: 5.9897x; 1.5859x over previous
//
#include <hip/hip_runtime.h>
#include <hip/hip_bf16.h>
#include <cstdint>
#include <cstddef>

typedef __hip_bfloat16 bf16;
typedef short short8 __attribute__((ext_vector_type(8)));
typedef float f32x4 __attribute__((ext_vector_type(4)));

#define GXC 100
#define GYC 100
#define GZC 20
#define NCELL (GXC*GYC*GZC)
#define MAXVX 60000
#define CAP 12

static inline int cdiv(int a, int b){ return (a+b-1)/b; }

__device__ __forceinline__ float b2f(bf16 v){ return __bfloat162float(v); }

// ---------- params gather ----------
struct P22 { const float* p[22]; };
__global__ void k_params(P22 ps, float* __restrict__ prm)
{
  const int ns[22] = {160,32,32,32,4096,128,128,128,64,64,128,128,128,128,256,256,512,512,512,256,256,256};
  int off = 0;
  for (int e=0;e<22;++e){
    const float* s = ps.p[e];
    const int n = ns[e];
    for (int i=threadIdx.x;i<n;i+=256) prm[off+i] = s[i];
    off += n;
  }
}
#define O_V1W 0
#define O_V1B 160
#define O_V1G 192
#define O_V1BT 224
#define O_V2W 256
#define O_V2B 4352
#define O_V2G 4480
#define O_V2BT 4608
#define O_SP1G 4736
#define O_SP1B 4800
#define O_SP2G 4864
#define O_SP2B 4992
#define O_SP3G 5120
#define O_SP3B 5248
#define O_SP4G 5376
#define O_SP4B 5632
#define O_BV1B 5888
#define O_BV1G 6400
#define O_BV1BT 6912
#define O_BV2B 7424
#define O_BV2G 7680
#define O_BV2BT 7936

// ---------- voxelize pass 1 ----------
__global__ void k_points(const float* __restrict__ pts, int N, unsigned* __restrict__ cnt)
{
  const int i = blockIdx.x*256 + threadIdx.x;
  if (i >= N) return;
  float x = pts[(size_t)i*5+0];
  float y = pts[(size_t)i*5+1];
  float z = pts[(size_t)i*5+2];
  float qx = (x - (-51.2f)) / 1.024f;
  float qy = (y - (-51.2f)) / 1.024f;
  float qz = (z - (-5.0f))  / 0.4f;
  int gx=(int)floorf(qx), gy=(int)floorf(qy), gz=(int)floorf(qz);
  if (x == 0.0f) return;
  if (gx<0||gx>=GXC||gy<0||gy>=GYC||gz<0||gz>=GZC) return;
  atomicAdd(&cnt[gx*(GYC*GZC) + gy*GZC + gz], 1u);
}

// ---------- rank occupied cells (cell-id order), first MAXVX kept ----------
__global__ __launch_bounds__(1024) void k_rank(const unsigned* __restrict__ cnt,
                                               int* __restrict__ keptList,
                                               int* __restrict__ map,
                                               unsigned* __restrict__ counters)
{
  __shared__ int wsum[16];
  __shared__ int sbase;
  const int tid = threadIdx.x;
  const int lane = tid & 63;
  const int w = tid >> 6;
  if (tid==0) sbase = 0;
  __syncthreads();
  for (int c0=0; c0<NCELL; c0+=1024){
    const int cell = c0 + tid;
    const int fl = (cell<NCELL && cnt[cell]>0u) ? 1 : 0;
    const unsigned long long m = __ballot(fl);
    const int wp = __popcll(m & ((1ull<<lane)-1ull));
    if (lane==0) wsum[w] = __popcll(m);
    __syncthreads();
    int wbase = 0;
    #pragma unroll
    for (int j=0;j<16;++j) wbase += (j<w) ? wsum[j] : 0;
    const int rank = sbase + wbase + wp;
    if (fl && rank < MAXVX){
      keptList[rank] = cell;
      const int ix=cell/2000, iy=(cell/20)%100, iz=cell%20;
      map[(iz*GYC+iy)*GXC+ix] = rank;
    }
    __syncthreads();
    if (tid==0){ int tot=0; for (int j=0;j<16;++j) tot+=wsum[j]; sbase+=tot; }
    __syncthreads();
  }
  if (tid==0) counters[0] = (unsigned)(sbase < MAXVX ? sbase : MAXVX);
}

// ---------- voxelize pass 2 ----------
__global__ void k_points2(const float* __restrict__ pts, int N,
                          const int* __restrict__ map,
                          unsigned* __restrict__ scnt, int* __restrict__ slots)
{
  const int i = blockIdx.x*256 + threadIdx.x;
  if (i >= N) return;
  float x = pts[(size_t)i*5+0];
  float y = pts[(size_t)i*5+1];
  float z = pts[(size_t)i*5+2];
  float qx = (x - (-51.2f)) / 1.024f;
  float qy = (y - (-51.2f)) / 1.024f;
  float qz = (z - (-5.0f))  / 0.4f;
  int gx=(int)floorf(qx), gy=(int)floorf(qy), gz=(int)floorf(qz);
  if (x == 0.0f) return;
  if (gx<0||gx>=GXC||gy<0||gy>=GYC||gz<0||gz>=GZC) return;
  const int didx = (gz*GYC+gy)*GXC+gx;
  const int r = map[didx];
  if (r < 0) return;
  unsigned pos = atomicAdd(&scnt[r], 1u);
  if (pos < CAP) slots[r*CAP + pos] = i;
}

// ---------- z128 ----------
__global__ void k_z128(const float* __restrict__ prm, float* __restrict__ z128)
{
  __shared__ float h1[32];
  const int tid = threadIdx.x;   // 128
  if (tid<32){ float s = prm[O_V1B+tid]*prm[O_V1G+tid]+prm[O_V1BT+tid]; h1[tid]=s>0.f?s:0.f; }
  __syncthreads();
  float s = prm[O_V2B+tid];
  for (int j=0;j<32;++j) s += prm[O_V2W+tid*32+j]*h1[j];
  s = s*prm[O_V2G+tid] + prm[O_V2BT+tid];
  z128[tid] = s>0.f?s:0.f;
}

// ---------- VFE: wave-per-voxel, barrier-free hot loop ----------
#define VPW 16
__global__ __launch_bounds__(256) void k_vfe(
  const float* __restrict__ pts, const float* __restrict__ prm,
  const unsigned* __restrict__ scnt, const int* __restrict__ slots,
  const int* __restrict__ keptList, const unsigned* __restrict__ counters,
  const float* __restrict__ z128,
  bf16* __restrict__ F0c, unsigned char* __restrict__ m0, int* __restrict__ list0)
{
  __shared__ float sW1[160], sb1[32], sg1[32], sB1[32];
  __shared__ float sW2[128*33];
  __shared__ float sb2[128], sg2[128], sB2[128], sz[128];
  __shared__ int sSrt[4][10];
  const int tid = threadIdx.x;
  for (int i=tid;i<160;i+=256) sW1[i]=prm[O_V1W+i];
  if (tid<32){ sb1[tid]=prm[O_V1B+tid]; sg1[tid]=prm[O_V1G+tid]; sB1[tid]=prm[O_V1BT+tid]; }
  for (int i=tid;i<4096;i+=256) sW2[(i>>5)*33 + (i&31)] = prm[O_V2W+i];
  if (tid<128){ sb2[tid]=prm[O_V2B+tid]; sg2[tid]=prm[O_V2G+tid]; sB2[tid]=prm[O_V2BT+tid]; sz[tid]=z128[tid]; }
  __syncthreads();
  const int wid = tid>>6, lane = tid&63;
  const int n = (int)counters[0];
  const int gid0 = ((int)blockIdx.x*4 + wid)*VPW;
  for (int v=0; v<VPW; ++v){
    const int gid = gid0 + v;
    if (gid >= n) break;
    const int total = (int)scnt[gid];
    const int cc = total<CAP?total:CAP;
    const int np = total<10?total:10;
    int myIdx = 0x7FFFFFFF;
    if (lane < cc) myIdx = slots[gid*CAP + lane];
    int rank = 0;
    for (int s=0;s<cc;++s){
      int vs = __shfl(myIdx, s);
      rank += (vs < myIdx) ? 1 : 0;
    }
    if (lane < cc && rank < np) sSrt[wid][rank] = myIdx;
    float vm0 = 0.f, vm1 = 0.f;
    for (int r=0;r<np;++r){
      const int pi = sSrt[wid][r];
      const float p0 = pts[(size_t)pi*5+0];
      const float p1 = pts[(size_t)pi*5+1];
      const float p2 = pts[(size_t)pi*5+2];
      const float p3 = pts[(size_t)pi*5+3];
      const float p4 = pts[(size_t)pi*5+4];
      float h = 0.f;
      if (lane < 32){
        float s = sb1[lane] + sW1[lane*5+0]*p0 + sW1[lane*5+1]*p1
                + sW1[lane*5+2]*p2 + sW1[lane*5+3]*p3 + sW1[lane*5+4]*p4;
        s = s*sg1[lane]+sB1[lane];
        h = s>0.f?s:0.f;
      }
      float s0 = sb2[lane], s1 = sb2[lane+64];
      #pragma unroll
      for (int j=0;j<32;++j){
        const float hj = __shfl(h, j);
        s0 += sW2[lane*33+j]*hj;
        s1 += sW2[(lane+64)*33+j]*hj;
      }
      s0 = s0*sg2[lane]+sB2[lane];    s0 = s0>0.f?s0:0.f;
      s1 = s1*sg2[lane+64]+sB2[lane+64]; s1 = s1>0.f?s1:0.f;
      vm0 = fmaxf(vm0, s0); vm1 = fmaxf(vm1, s1);
    }
    if (np<10){ vm0 = fmaxf(vm0, sz[lane]); vm1 = fmaxf(vm1, sz[lane+64]); }
    F0c[(size_t)gid*128 + lane]      = __float2bfloat16(vm0);
    F0c[(size_t)gid*128 + lane + 64] = __float2bfloat16(vm1);
    if (lane==0){
      const int cell = keptList[gid];
      const int ix=cell/2000, iy=(cell/20)%100, iz=cell%20;
      const int didx = (iz*GYC+iy)*GXC+ix;
      m0[didx]=1; list0[gid]=didx;
    }
  }
}

// ---------- occupancy pooling ----------
__global__ void k_pool(const unsigned char* __restrict__ mIn, unsigned char* __restrict__ mOut,
                       int* __restrict__ listOut, unsigned* __restrict__ counter,
                       int IZ,int IY,int IX,int OZ,int OY,int OX)
{
  const int s = blockIdx.x*256+threadIdx.x;
  if (s >= OZ*OY*OX) return;
  const int ox=s%OX, oy=(s/OX)%OY, oz=s/(OX*OY);
  bool any=false;
  for (int dz=0;dz<3;++dz){ int nz=oz*2+dz-1; if(nz<0||nz>=IZ)continue;
    for (int dy=0;dy<3;++dy){ int ny=oy*2+dy-1; if(ny<0||ny>=IY)continue;
      for (int dx=0;dx<3;++dx){ int nx=ox*2+dx-1; if(nx<0||nx>=IX)continue;
        any = any || (mIn[(nz*IY+ny)*IX+nx] != 0);
      }}}
  if (any){ mOut[s]=1; unsigned p=atomicAdd(counter,1u); listOut[p]=s; }
}

// ---------- MFMA weight re-layout: O,CIN,KV f32 -> B-fragment bf16 [ct][ks][lane][8] ----------
__global__ void k_wtm(const float* __restrict__ src, bf16* __restrict__ dst,
                      int COUT, int CIN, int KV)
{
  const int K = KV*CIN;
  const int idx = blockIdx.x*256+threadIdx.x;
  if (idx >= COUT*K) return;
  const int j = idx & 7;
  const int l = (idx >> 3) & 63;
  const int rest = idx >> 9;           // ct*KS + ks
  const int KS = K/32;
  const int ks = rest % KS;
  const int ct = rest / KS;
  const int o = ct*16 + (l & 15);
  const int k = ks*32 + ((l>>4)<<3) + j;
  const int kk = k / CIN;
  const int ci = k % CIN;
  dst[idx] = __float2bfloat16(src[((size_t)o*CIN + ci)*KV + kk]);
}

// ---------- MFMA implicit-GEMM masked 3D conv (dual-acc ILP) ----------
template<int CIN, int COUT, int STRIDE, int INMODE, int OUTMODE>
__global__ __launch_bounds__(256) void k_conv3m(
    const bf16* __restrict__ inP, bf16* __restrict__ out,
    const bf16* __restrict__ WtM,
    const float* __restrict__ gam, const float* __restrict__ bet,
    const int* __restrict__ list, const unsigned* __restrict__ nPtr,
    const int* __restrict__ map,
    int IZ, int IY, int IX, int OY, int OX)
{
  constexpr int K  = 27*CIN;
  constexpr int KS = K/32;
  constexpr int CS = CIN/32;
  __shared__ int sMi[16][27];
  __shared__ int sSite[16];
  const int n = (int)(*nPtr);
  const int base = (int)blockIdx.x * 16;
  if (base >= n) return;
  const int tid = threadIdx.x;
  for (int i=tid; i<16*27; i+=256){
    const int r = i/27, kk = i%27;
    int mi = -1, site = -1;
    if (base + r < n){
      site = list[base+r];
      const int ox = site % OX, oy = (site/OX)%OY, oz = site/(OX*OY);
      const int dz=kk/9, dy=(kk/3)%3, dx=kk%3;
      const int nz=oz*STRIDE+dz-1, ny=oy*STRIDE+dy-1, nx=ox*STRIDE+dx-1;
      if (nz>=0&&nz<IZ&&ny>=0&&ny<IY&&nx>=0&&nx<IX){
        const int nd=(nz*IY+ny)*IX+nx;
        mi = (INMODE==1) ? map[nd] : nd;
      }
    }
    if (kk==0) sSite[r] = site;
    sMi[r][kk] = mi;
  }
  __syncthreads();
  const int wid = tid>>6, lane = tid&63;
  const int ct = (int)blockIdx.y*4 + wid;
  const int row = lane & 15;
  const int koff = (lane>>4)<<3;
  const bf16* wptr = WtM + (((size_t)ct*KS)*64 + lane)*8;
  f32x4 acc0 = {0.f,0.f,0.f,0.f};
  f32x4 acc1 = {0.f,0.f,0.f,0.f};
  for (int kk=0; kk<27; ++kk){
    const int mi = sMi[row][kk];
    const bf16* arow = inP + (size_t)(mi<0?0:mi)*CIN + koff;
    #pragma unroll
    for (int cs=0; cs<CS; ++cs){
      union { uint4 u; short8 v; } A;
      A.u = make_uint4(0u,0u,0u,0u);
      if (mi >= 0) A.u = *(const uint4*)(arow + cs*32);
      union { uint4 u; short8 v; } B;
      B.u = *(const uint4*)wptr;
      wptr += 64*8;
      if ((cs & 1) == 0) acc0 = __builtin_amdgcn_mfma_f32_16x16x32_bf16(A.v, B.v, acc0, 0, 0, 0);
      else               acc1 = __builtin_amdgcn_mfma_f32_16x16x32_bf16(A.v, B.v, acc1, 0, 0, 0);
    }
  }
  f32x4 acc = acc0 + acc1;
  const int c = ct*16 + (lane & 15);
  const float gs = gam[c], bs = bet[c];
  #pragma unroll
  for (int j=0;j<4;++j){
    const int r = ((lane>>4)<<2) + j;
    const int site = sSite[r];
    if (site < 0) continue;
    float vv = acc[j]*gs + bs; vv = vv>0.f?vv:0.f;
    size_t oidx;
    if constexpr (OUTMODE==2){
      const int ox2=site%OX, oy2=(site/OX)%OY, oz2=site/(OX*OY);
      oidx = ((size_t)(oy2*OX+ox2)*5 + oz2)*COUT + c;
    } else {
      oidx = (size_t)site*COUT + c;
    }
    out[oidx] = __float2bfloat16(vv);
  }
}

// ---------- MFMA implicit-GEMM dense 2D BEV conv (25x25, pad 1) ----------
// FINAL=false: out bf16 [pixel][COUT]; FINAL=true: out f32 (C,H,W) + bias.
template<int CIN, int COUT, bool FINAL, typename TOUT>
__global__ __launch_bounds__(256) void k_conv2m(
    const bf16* __restrict__ in, TOUT* __restrict__ out,
    const bf16* __restrict__ WtM,
    const float* __restrict__ bias, const float* __restrict__ gam, const float* __restrict__ bet)
{
  constexpr int K  = 9*CIN;
  constexpr int KS = K/32;
  constexpr int CS = CIN/32;
  __shared__ int sOff[16][9];
  const int tid = threadIdx.x;
  const int mt = (int)blockIdx.x;        // 16-pixel tile, 40 tiles cover 625
  for (int i=tid; i<16*9; i+=256){
    const int r = i/9, kk = i%9;
    const int pi = mt*16 + r;
    int off = -1;
    if (pi < 625){
      const int y = pi/25, x = pi%25;
      const int ry = y-1+kk/3, cx = x-1+kk%3;
      if (ry>=0 && ry<25 && cx>=0 && cx<25) off = ry*25+cx;
    }
    sOff[r][kk] = off;
  }
  __syncthreads();
  const int wid = tid>>6, lane = tid&63;
  const int ct = (int)blockIdx.y*4 + wid;
  const int row = lane & 15;
  const int koff = (lane>>4)<<3;
  const bf16* wptr = WtM + (((size_t)ct*KS)*64 + lane)*8;
  f32x4 acc0 = {0.f,0.f,0.f,0.f};
  f32x4 acc1 = {0.f,0.f,0.f,0.f};
  for (int kk=0; kk<9; ++kk){
    const int off = sOff[row][kk];
    const bf16* arow = in + (size_t)(off<0?0:off)*CIN + koff;
    #pragma unroll 4
    for (int cs=0; cs<CS; ++cs){
      union { uint4 u; short8 v; } A;
      A.u = make_uint4(0u,0u,0u,0u);
      if (off >= 0) A.u = *(const uint4*)(arow + cs*32);
      union { uint4 u; short8 v; } B;
      B.u = *(const uint4*)wptr;
      wptr += 64*8;
      if ((cs & 1) == 0) acc0 = __builtin_amdgcn_mfma_f32_16x16x32_bf16(A.v, B.v, acc0, 0, 0, 0);
      else               acc1 = __builtin_amdgcn_mfma_f32_16x16x32_bf16(A.v, B.v, acc1, 0, 0, 0);
    }
  }
  f32x4 acc = acc0 + acc1;
  const int c = ct*16 + (lane & 15);
  const float bi = bias[c], gs = gam[c], bs = bet[c];
  #pragma unroll
  for (int j=0;j<4;++j){
    const int r = ((lane>>4)<<2) + j;
    const int pi = mt*16 + r;
    if (pi >= 625) continue;
    float vv = (acc[j]+bi)*gs + bs; vv = vv>0.f?vv:0.f;
    if constexpr (FINAL)
      ((float*)out)[(size_t)c*625 + pi] = vv;          // (C,H,W) f32
    else
      ((bf16*)out)[(size_t)pi*COUT + c] = __float2bfloat16(vv);
  }
}

// ---------- launch ----------
extern "C" void kernel_launch(void* const* d_in, const int* in_sizes, int n_in,
                              void* d_out, int out_size, void* d_ws, size_t ws_size,
                              hipStream_t stream)
{
  (void)n_in; (void)out_size; (void)ws_size;
  const int N = in_sizes[0] / 5;

  char* p = (char*)d_ws;
  size_t off = 0;
  auto carve = [&](size_t bytes)->char*{
    char* r = p + off;
    off += (bytes + 255) & ~(size_t)255;
    return r;
  };
  // ---- zero region ----
  unsigned*      counters = (unsigned*)     carve(256);
  unsigned*      cnt      = (unsigned*)     carve((size_t)NCELL*4);
  unsigned*      scnt     = (unsigned*)     carve((size_t)MAXVX*4);
  unsigned char* m0       = (unsigned char*)carve(NCELL);
  unsigned char* m1       = (unsigned char*)carve(25000);
  unsigned char* m2       = (unsigned char*)carve(3125);
  bf16*  F0c   = (bf16*) carve((size_t)MAXVX*128*2);
  bf16*  F1    = (bf16*) carve((size_t)NCELL*64*2);     // dense (20,100,100,64)
  bf16*  F2    = (bf16*) carve((size_t)25000*128*2);
  bf16*  F3    = (bf16*) carve((size_t)25000*128*2);
  bf16*  F4    = (bf16*) carve((size_t)3125*256*2);
  bf16*  bev1  = (bf16*) carve((size_t)625*512*2);
  const size_t zero_total = off;
  // ---- non-zero ----
  int*   map      = (int*)  carve((size_t)NCELL*4);      // 0xFF
  int*   keptList = (int*)  carve((size_t)MAXVX*4);
  int*   list0    = (int*)  carve((size_t)MAXVX*4);
  int*   list1    = (int*)  carve((size_t)25000*4);
  int*   list2    = (int*)  carve((size_t)3125*4);
  int*   slots    = (int*)  carve((size_t)MAXVX*CAP*4);
  float* prm      = (float*)carve(8192*4);
  float* z128     = (float*)carve(512);
  bf16*  Wm1      = (bf16*) carve((size_t)64*27*128*2);
  bf16*  Wm2      = (bf16*) carve((size_t)128*27*64*2);
  bf16*  Wm3      = (bf16*) carve((size_t)128*27*128*2);
  bf16*  Wm4      = (bf16*) carve((size_t)256*27*128*2);
  bf16*  WmB1     = (bf16*) carve((size_t)512*9*1280*2);
  bf16*  WmB2     = (bf16*) carve((size_t)256*9*512*2);

  hipMemsetAsync(d_ws, 0, zero_total, stream);
  hipMemsetAsync(map, 0xFF, (size_t)NCELL*4, stream);

  P22 ps;
  const int prmIdx[22] = {1,2,3,4,5,6,7,8, 10,11, 13,14, 16,17, 19,20, 22,23,24, 26,27,28};
  for (int e=0;e<22;++e) ps.p[e] = (const float*)d_in[prmIdx[e]];
  k_params<<<1,256,0,stream>>>(ps, prm);
  k_z128<<<1,128,0,stream>>>(prm, z128);
  k_wtm<<<cdiv(64*27*128,256),256,0,stream>>>((const float*)d_in[9],  Wm1, 64, 128, 27);
  k_wtm<<<cdiv(128*27*64,256),256,0,stream>>>((const float*)d_in[12], Wm2, 128, 64, 27);
  k_wtm<<<cdiv(128*27*128,256),256,0,stream>>>((const float*)d_in[15], Wm3, 128, 128, 27);
  k_wtm<<<cdiv(256*27*128,256),256,0,stream>>>((const float*)d_in[18], Wm4, 256, 128, 27);
  k_wtm<<<cdiv(512*9*1280,256),256,0,stream>>>((const float*)d_in[21], WmB1, 512, 1280, 9);
  k_wtm<<<cdiv(256*9*512,256),256,0,stream>>>((const float*)d_in[25], WmB2, 256, 512, 9);

  const float* pts = (const float*)d_in[0];
  k_points<<<cdiv(N,256),256,0,stream>>>(pts, N, cnt);
  k_rank<<<1,1024,0,stream>>>(cnt, keptList, map, counters);
  k_points2<<<cdiv(N,256),256,0,stream>>>(pts, N, map, scnt, slots);
  k_vfe<<<cdiv(MAXVX,4*VPW),256,0,stream>>>(pts, prm, scnt, slots, keptList, counters,
                                            z128, F0c, m0, list0);

  k_pool<<<cdiv(25000,256),256,0,stream>>>(m0, m1, list1, counters+1, 20,100,100, 10,50,50);
  k_pool<<<cdiv(3125,256),256,0,stream>>>(m1, m2, list2, counters+2, 10,50,50, 5,25,25);

  // sp1: compact-in via map -> dense F1.  M=60000, N=64, K=3456
  k_conv3m<128,64,1,1,0><<<dim3(cdiv(MAXVX,16),1),256,0,stream>>>(
      F0c, F1, Wm1, prm+O_SP1G, prm+O_SP1B, list0, counters+0, map, 20,100,100, 100,100);
  // sp2: dense F1 -> dense F2 (stride 2)
  k_conv3m<64,128,2,0,0><<<dim3(cdiv(25000,16),2),256,0,stream>>>(
      F1, F2, Wm2, prm+O_SP2G, prm+O_SP2B, list1, counters+1, map, 20,100,100, 50,50);
  // sp3: dense F2 -> dense F3
  k_conv3m<128,128,1,0,0><<<dim3(cdiv(25000,16),2),256,0,stream>>>(
      F2, F3, Wm3, prm+O_SP3G, prm+O_SP3B, list1, counters+1, map, 10,50,50, 50,50);
  // sp4: dense F3 -> BEV F4 (stride 2)
  k_conv3m<128,256,2,0,2><<<dim3(cdiv(3125,16),4),256,0,stream>>>(
      F3, F4, Wm4, prm+O_SP4G, prm+O_SP4B, list2, counters+2, map, 10,50,50, 25,25);

  // BEV head on MFMA: bev1 (M=625,N=512,K=11520), bev2 (M=625,N=256,K=4608)
  k_conv2m<1280,512,false,bf16><<<dim3(40,8),256,0,stream>>>(
      F4, bev1, WmB1, prm+O_BV1B, prm+O_BV1G, prm+O_BV1BT);
  k_conv2m<512,256,true,float><<<dim3(40,4),256,0,stream>>>(
      bev1, (float*)d_out, WmB2, prm+O_BV2B, prm+O_BV2G, prm+O_BV2BT);
}

// Round 13
// 748.579 us; speedup vs baseline: 7.2484x; 1.2101x over previous
//
#include <hip/hip_runtime.h>
#include <hip/hip_bf16.h>
#include <cstdint>
#include <cstddef>

typedef __hip_bfloat16 bf16;
typedef short short8 __attribute__((ext_vector_type(8)));
typedef float f32x4 __attribute__((ext_vector_type(4)));

#define GXC 100
#define GYC 100
#define GZC 20
#define NCELL (GXC*GYC*GZC)
#define MAXVX 60000
#define CAP 12

static inline int cdiv(int a, int b){ return (a+b-1)/b; }

__device__ __forceinline__ float b2f(bf16 v){ return __bfloat162float(v); }

// ---------- params gather ----------
struct P22 { const float* p[22]; };
__global__ void k_params(P22 ps, float* __restrict__ prm)
{
  const int ns[22] = {160,32,32,32,4096,128,128,128,64,64,128,128,128,128,256,256,512,512,512,256,256,256};
  int off = 0;
  for (int e=0;e<22;++e){
    const float* s = ps.p[e];
    const int n = ns[e];
    for (int i=threadIdx.x;i<n;i+=256) prm[off+i] = s[i];
    off += n;
  }
}
#define O_V1W 0
#define O_V1B 160
#define O_V1G 192
#define O_V1BT 224
#define O_V2W 256
#define O_V2B 4352
#define O_V2G 4480
#define O_V2BT 4608
#define O_SP1G 4736
#define O_SP1B 4800
#define O_SP2G 4864
#define O_SP2B 4992
#define O_SP3G 5120
#define O_SP3B 5248
#define O_SP4G 5376
#define O_SP4B 5632
#define O_BV1B 5888
#define O_BV1G 6400
#define O_BV1BT 6912
#define O_BV2B 7424
#define O_BV2G 7680
#define O_BV2BT 7936

// ---------- voxelize pass 1 ----------
__global__ void k_points(const float* __restrict__ pts, int N, unsigned* __restrict__ cnt)
{
  const int i = blockIdx.x*256 + threadIdx.x;
  if (i >= N) return;
  float x = pts[(size_t)i*5+0];
  float y = pts[(size_t)i*5+1];
  float z = pts[(size_t)i*5+2];
  float qx = (x - (-51.2f)) / 1.024f;
  float qy = (y - (-51.2f)) / 1.024f;
  float qz = (z - (-5.0f))  / 0.4f;
  int gx=(int)floorf(qx), gy=(int)floorf(qy), gz=(int)floorf(qz);
  if (x == 0.0f) return;
  if (gx<0||gx>=GXC||gy<0||gy>=GYC||gz<0||gz>=GZC) return;
  atomicAdd(&cnt[gx*(GYC*GZC) + gy*GZC + gz], 1u);
}

// ---------- rank occupied cells (cell-id order), first MAXVX kept ----------
__global__ __launch_bounds__(1024) void k_rank(const unsigned* __restrict__ cnt,
                                               int* __restrict__ keptList,
                                               int* __restrict__ map,
                                               unsigned* __restrict__ counters)
{
  __shared__ int wsum[16];
  __shared__ int sbase;
  const int tid = threadIdx.x;
  const int lane = tid & 63;
  const int w = tid >> 6;
  if (tid==0) sbase = 0;
  __syncthreads();
  for (int c0=0; c0<NCELL; c0+=1024){
    const int cell = c0 + tid;
    const int fl = (cell<NCELL && cnt[cell]>0u) ? 1 : 0;
    const unsigned long long m = __ballot(fl);
    const int wp = __popcll(m & ((1ull<<lane)-1ull));
    if (lane==0) wsum[w] = __popcll(m);
    __syncthreads();
    int wbase = 0;
    #pragma unroll
    for (int j=0;j<16;++j) wbase += (j<w) ? wsum[j] : 0;
    const int rank = sbase + wbase + wp;
    if (fl && rank < MAXVX){
      keptList[rank] = cell;
      const int ix=cell/2000, iy=(cell/20)%100, iz=cell%20;
      map[(iz*GYC+iy)*GXC+ix] = rank;
    }
    __syncthreads();
    if (tid==0){ int tot=0; for (int j=0;j<16;++j) tot+=wsum[j]; sbase+=tot; }
    __syncthreads();
  }
  if (tid==0) counters[0] = (unsigned)(sbase < MAXVX ? sbase : MAXVX);
}

// ---------- voxelize pass 2 ----------
__global__ void k_points2(const float* __restrict__ pts, int N,
                          const int* __restrict__ map,
                          unsigned* __restrict__ scnt, int* __restrict__ slots)
{
  const int i = blockIdx.x*256 + threadIdx.x;
  if (i >= N) return;
  float x = pts[(size_t)i*5+0];
  float y = pts[(size_t)i*5+1];
  float z = pts[(size_t)i*5+2];
  float qx = (x - (-51.2f)) / 1.024f;
  float qy = (y - (-51.2f)) / 1.024f;
  float qz = (z - (-5.0f))  / 0.4f;
  int gx=(int)floorf(qx), gy=(int)floorf(qy), gz=(int)floorf(qz);
  if (x == 0.0f) return;
  if (gx<0||gx>=GXC||gy<0||gy>=GYC||gz<0||gz>=GZC) return;
  const int didx = (gz*GYC+gy)*GXC+gx;
  const int r = map[didx];
  if (r < 0) return;
  unsigned pos = atomicAdd(&scnt[r], 1u);
  if (pos < CAP) slots[r*CAP + pos] = i;
}

// ---------- z128 ----------
__global__ void k_z128(const float* __restrict__ prm, float* __restrict__ z128)
{
  __shared__ float h1[32];
  const int tid = threadIdx.x;   // 128
  if (tid<32){ float s = prm[O_V1B+tid]*prm[O_V1G+tid]+prm[O_V1BT+tid]; h1[tid]=s>0.f?s:0.f; }
  __syncthreads();
  float s = prm[O_V2B+tid];
  for (int j=0;j<32;++j) s += prm[O_V2W+tid*32+j]*h1[j];
  s = s*prm[O_V2G+tid] + prm[O_V2BT+tid];
  z128[tid] = s>0.f?s:0.f;
}

// ---------- VFE: wave-per-voxel ----------
#define VPW 16
__global__ __launch_bounds__(256) void k_vfe(
  const float* __restrict__ pts, const float* __restrict__ prm,
  const unsigned* __restrict__ scnt, const int* __restrict__ slots,
  const int* __restrict__ keptList, const unsigned* __restrict__ counters,
  const float* __restrict__ z128,
  bf16* __restrict__ F0c, unsigned char* __restrict__ m0, int* __restrict__ list0)
{
  __shared__ float sW1[160], sb1[32], sg1[32], sB1[32];
  __shared__ float sW2[128*33];
  __shared__ float sb2[128], sg2[128], sB2[128], sz[128];
  __shared__ int sSrt[4][10];
  const int tid = threadIdx.x;
  for (int i=tid;i<160;i+=256) sW1[i]=prm[O_V1W+i];
  if (tid<32){ sb1[tid]=prm[O_V1B+tid]; sg1[tid]=prm[O_V1G+tid]; sB1[tid]=prm[O_V1BT+tid]; }
  for (int i=tid;i<4096;i+=256) sW2[(i>>5)*33 + (i&31)] = prm[O_V2W+i];
  if (tid<128){ sb2[tid]=prm[O_V2B+tid]; sg2[tid]=prm[O_V2G+tid]; sB2[tid]=prm[O_V2BT+tid]; sz[tid]=z128[tid]; }
  __syncthreads();
  const int wid = tid>>6, lane = tid&63;
  const int n = (int)counters[0];
  const int gid0 = ((int)blockIdx.x*4 + wid)*VPW;
  for (int v=0; v<VPW; ++v){
    const int gid = gid0 + v;
    if (gid >= n) break;
    const int total = (int)scnt[gid];
    const int cc = total<CAP?total:CAP;
    const int np = total<10?total:10;
    int myIdx = 0x7FFFFFFF;
    if (lane < cc) myIdx = slots[gid*CAP + lane];
    int rank = 0;
    for (int s=0;s<cc;++s){
      int vs = __shfl(myIdx, s);
      rank += (vs < myIdx) ? 1 : 0;
    }
    if (lane < cc && rank < np) sSrt[wid][rank] = myIdx;
    float vm0 = 0.f, vm1 = 0.f;
    for (int r=0;r<np;++r){
      const int pi = sSrt[wid][r];
      const float p0 = pts[(size_t)pi*5+0];
      const float p1 = pts[(size_t)pi*5+1];
      const float p2 = pts[(size_t)pi*5+2];
      const float p3 = pts[(size_t)pi*5+3];
      const float p4 = pts[(size_t)pi*5+4];
      float h = 0.f;
      if (lane < 32){
        float s = sb1[lane] + sW1[lane*5+0]*p0 + sW1[lane*5+1]*p1
                + sW1[lane*5+2]*p2 + sW1[lane*5+3]*p3 + sW1[lane*5+4]*p4;
        s = s*sg1[lane]+sB1[lane];
        h = s>0.f?s:0.f;
      }
      float s0 = sb2[lane], s1 = sb2[lane+64];
      #pragma unroll
      for (int j=0;j<32;++j){
        const float hj = __shfl(h, j);
        s0 += sW2[lane*33+j]*hj;
        s1 += sW2[(lane+64)*33+j]*hj;
      }
      s0 = s0*sg2[lane]+sB2[lane];    s0 = s0>0.f?s0:0.f;
      s1 = s1*sg2[lane+64]+sB2[lane+64]; s1 = s1>0.f?s1:0.f;
      vm0 = fmaxf(vm0, s0); vm1 = fmaxf(vm1, s1);
    }
    if (np<10){ vm0 = fmaxf(vm0, sz[lane]); vm1 = fmaxf(vm1, sz[lane+64]); }
    F0c[(size_t)gid*128 + lane]      = __float2bfloat16(vm0);
    F0c[(size_t)gid*128 + lane + 64] = __float2bfloat16(vm1);
    if (lane==0){
      const int cell = keptList[gid];
      const int ix=cell/2000, iy=(cell/20)%100, iz=cell%20;
      const int didx = (iz*GYC+iy)*GXC+ix;
      m0[didx]=1; list0[gid]=didx;
    }
  }
}

// ---------- occupancy pooling ----------
__global__ void k_pool(const unsigned char* __restrict__ mIn, unsigned char* __restrict__ mOut,
                       int* __restrict__ listOut, unsigned* __restrict__ counter,
                       int IZ,int IY,int IX,int OZ,int OY,int OX)
{
  const int s = blockIdx.x*256+threadIdx.x;
  if (s >= OZ*OY*OX) return;
  const int ox=s%OX, oy=(s/OX)%OY, oz=s/(OX*OY);
  bool any=false;
  for (int dz=0;dz<3;++dz){ int nz=oz*2+dz-1; if(nz<0||nz>=IZ)continue;
    for (int dy=0;dy<3;++dy){ int ny=oy*2+dy-1; if(ny<0||ny>=IY)continue;
      for (int dx=0;dx<3;++dx){ int nx=ox*2+dx-1; if(nx<0||nx>=IX)continue;
        any = any || (mIn[(nz*IY+ny)*IX+nx] != 0);
      }}}
  if (any){ mOut[s]=1; unsigned p=atomicAdd(counter,1u); listOut[p]=s; }
}

// ---------- MFMA weight re-layout: O,CIN,KV f32 -> B-fragment bf16 [ct][ks][lane][8] ----------
__global__ void k_wtm(const float* __restrict__ src, bf16* __restrict__ dst,
                      int COUT, int CIN, int KV)
{
  const int K = KV*CIN;
  const int idx = blockIdx.x*256+threadIdx.x;
  if (idx >= COUT*K) return;
  const int j = idx & 7;
  const int l = (idx >> 3) & 63;
  const int rest = idx >> 9;           // ct*KS + ks
  const int KS = K/32;
  const int ks = rest % KS;
  const int ct = rest / KS;
  const int o = ct*16 + (l & 15);
  const int k = ks*32 + ((l>>4)<<3) + j;
  const int kk = k / CIN;
  const int ci = k % CIN;
  dst[idx] = __float2bfloat16(src[((size_t)o*CIN + ci)*KV + kk]);
}

// ---------- MFMA conv, waves-on-M, 4 ct per wave (1A x 4B register blocking) ----------
// INMODE 0: dense input grid; 1: compact via map.  Dense site-major output.
template<int CIN, int COUT, int STRIDE, int INMODE>
__global__ __launch_bounds__(256) void k_conv3m4(
    const bf16* __restrict__ inP, bf16* __restrict__ out,
    const bf16* __restrict__ WtM,
    const float* __restrict__ gam, const float* __restrict__ bet,
    const int* __restrict__ list, const unsigned* __restrict__ nPtr,
    const int* __restrict__ map,
    int IZ, int IY, int IX, int OY, int OX)
{
  constexpr int KS = 27*CIN/32;
  constexpr int CS = CIN/32;
  __shared__ int sMi[64][27];
  __shared__ int sSite[64];
  const int n = (int)(*nPtr);
  const int base = (int)blockIdx.x * 64;
  if (base >= n) return;
  const int tid = threadIdx.x;
  for (int i=tid; i<64*27; i+=256){
    const int r = i/27, kk = i%27;
    int mi = -1, site = -1;
    if (base + r < n){
      site = list[base+r];
      const int ox = site % OX, oy = (site/OX)%OY, oz = site/(OX*OY);
      const int dz=kk/9, dy=(kk/3)%3, dx=kk%3;
      const int nz=oz*STRIDE+dz-1, ny=oy*STRIDE+dy-1, nx=ox*STRIDE+dx-1;
      if (nz>=0&&nz<IZ&&ny>=0&&ny<IY&&nx>=0&&nx<IX){
        const int nd=(nz*IY+ny)*IX+nx;
        mi = (INMODE==1) ? map[nd] : nd;
      }
    }
    if (kk==0) sSite[r] = site;
    sMi[r][kk] = mi;
  }
  __syncthreads();
  const int wid = tid>>6, lane = tid&63;
  const int row = lane & 15;
  const int mrow = wid*16 + row;
  const int koff = (lane>>4)<<3;
  const int ct0 = (int)blockIdx.y*4;
  const bf16* w0 = WtM + (((size_t)(ct0+0)*KS)*64 + lane)*8;
  const bf16* w1 = WtM + (((size_t)(ct0+1)*KS)*64 + lane)*8;
  const bf16* w2 = WtM + (((size_t)(ct0+2)*KS)*64 + lane)*8;
  const bf16* w3 = WtM + (((size_t)(ct0+3)*KS)*64 + lane)*8;
  f32x4 acc0 = {0.f,0.f,0.f,0.f};
  f32x4 acc1 = {0.f,0.f,0.f,0.f};
  f32x4 acc2 = {0.f,0.f,0.f,0.f};
  f32x4 acc3 = {0.f,0.f,0.f,0.f};
  size_t wo = 0;
  for (int kk=0; kk<27; ++kk){
    const int mi = sMi[mrow][kk];
    const bf16* arow = inP + (size_t)(mi<0?0:mi)*CIN + koff;
    #pragma unroll
    for (int cs=0; cs<CS; ++cs){
      union { uint4 u; short8 v; } A;
      A.u = make_uint4(0u,0u,0u,0u);
      if (mi >= 0) A.u = *(const uint4*)(arow + cs*32);
      union { uint4 u; short8 v; } B0, B1, B2, B3;
      B0.u = *(const uint4*)(w0 + wo);
      B1.u = *(const uint4*)(w1 + wo);
      B2.u = *(const uint4*)(w2 + wo);
      B3.u = *(const uint4*)(w3 + wo);
      wo += 64*8;
      acc0 = __builtin_amdgcn_mfma_f32_16x16x32_bf16(A.v, B0.v, acc0, 0, 0, 0);
      acc1 = __builtin_amdgcn_mfma_f32_16x16x32_bf16(A.v, B1.v, acc1, 0, 0, 0);
      acc2 = __builtin_amdgcn_mfma_f32_16x16x32_bf16(A.v, B2.v, acc2, 0, 0, 0);
      acc3 = __builtin_amdgcn_mfma_f32_16x16x32_bf16(A.v, B3.v, acc3, 0, 0, 0);
    }
  }
  #pragma unroll
  for (int q=0;q<4;++q){
    const f32x4 acc = (q==0)?acc0:((q==1)?acc1:((q==2)?acc2:acc3));
    const int c = (ct0+q)*16 + row;
    const float gs = gam[c], bs = bet[c];
    #pragma unroll
    for (int j=0;j<4;++j){
      const int r = ((lane>>4)<<2) + j;
      const int site = sSite[wid*16 + r];
      if (site < 0) continue;
      float vv = acc[j]*gs + bs; vv = vv>0.f?vv:0.f;
      out[(size_t)site*COUT + c] = __float2bfloat16(vv);
    }
  }
}

// ---------- MFMA conv, waves-on-N (small-site layers), dual acc. OUTMODE 2 = BEV ----------
template<int CIN, int COUT, int STRIDE, int INMODE, int OUTMODE>
__global__ __launch_bounds__(256) void k_conv3m(
    const bf16* __restrict__ inP, bf16* __restrict__ out,
    const bf16* __restrict__ WtM,
    const float* __restrict__ gam, const float* __restrict__ bet,
    const int* __restrict__ list, const unsigned* __restrict__ nPtr,
    const int* __restrict__ map,
    int IZ, int IY, int IX, int OY, int OX)
{
  constexpr int KS = 27*CIN/32;
  constexpr int CS = CIN/32;
  __shared__ int sMi[16][27];
  __shared__ int sSite[16];
  const int n = (int)(*nPtr);
  const int base = (int)blockIdx.x * 16;
  if (base >= n) return;
  const int tid = threadIdx.x;
  for (int i=tid; i<16*27; i+=256){
    const int r = i/27, kk = i%27;
    int mi = -1, site = -1;
    if (base + r < n){
      site = list[base+r];
      const int ox = site % OX, oy = (site/OX)%OY, oz = site/(OX*OY);
      const int dz=kk/9, dy=(kk/3)%3, dx=kk%3;
      const int nz=oz*STRIDE+dz-1, ny=oy*STRIDE+dy-1, nx=ox*STRIDE+dx-1;
      if (nz>=0&&nz<IZ&&ny>=0&&ny<IY&&nx>=0&&nx<IX){
        const int nd=(nz*IY+ny)*IX+nx;
        mi = (INMODE==1) ? map[nd] : nd;
      }
    }
    if (kk==0) sSite[r] = site;
    sMi[r][kk] = mi;
  }
  __syncthreads();
  const int wid = tid>>6, lane = tid&63;
  const int ct = (int)blockIdx.y*4 + wid;
  const int row = lane & 15;
  const int koff = (lane>>4)<<3;
  const bf16* wptr = WtM + (((size_t)ct*KS)*64 + lane)*8;
  f32x4 acc0 = {0.f,0.f,0.f,0.f};
  f32x4 acc1 = {0.f,0.f,0.f,0.f};
  for (int kk=0; kk<27; ++kk){
    const int mi = sMi[row][kk];
    const bf16* arow = inP + (size_t)(mi<0?0:mi)*CIN + koff;
    #pragma unroll
    for (int cs=0; cs<CS; ++cs){
      union { uint4 u; short8 v; } A;
      A.u = make_uint4(0u,0u,0u,0u);
      if (mi >= 0) A.u = *(const uint4*)(arow + cs*32);
      union { uint4 u; short8 v; } B;
      B.u = *(const uint4*)wptr;
      wptr += 64*8;
      if ((cs & 1) == 0) acc0 = __builtin_amdgcn_mfma_f32_16x16x32_bf16(A.v, B.v, acc0, 0, 0, 0);
      else               acc1 = __builtin_amdgcn_mfma_f32_16x16x32_bf16(A.v, B.v, acc1, 0, 0, 0);
    }
  }
  f32x4 acc = acc0 + acc1;
  const int c = ct*16 + (lane & 15);
  const float gs = gam[c], bs = bet[c];
  #pragma unroll
  for (int j=0;j<4;++j){
    const int r = ((lane>>4)<<2) + j;
    const int site = sSite[r];
    if (site < 0) continue;
    float vv = acc[j]*gs + bs; vv = vv>0.f?vv:0.f;
    size_t oidx;
    if constexpr (OUTMODE==2){
      const int ox2=site%OX, oy2=(site/OX)%OY, oz2=site/(OX*OY);
      oidx = ((size_t)(oy2*OX+ox2)*5 + oz2)*COUT + c;
    } else {
      oidx = (size_t)site*COUT + c;
    }
    out[oidx] = __float2bfloat16(vv);
  }
}

// ---------- MFMA dense 2D BEV conv (25x25, pad 1) ----------
template<int CIN, int COUT, bool FINAL, typename TOUT>
__global__ __launch_bounds__(256) void k_conv2m(
    const bf16* __restrict__ in, TOUT* __restrict__ out,
    const bf16* __restrict__ WtM,
    const float* __restrict__ bias, const float* __restrict__ gam, const float* __restrict__ bet)
{
  constexpr int KS = 9*CIN/32;
  constexpr int CS = CIN/32;
  __shared__ int sOff[16][9];
  const int tid = threadIdx.x;
  const int mt = (int)blockIdx.x;
  for (int i=tid; i<16*9; i+=256){
    const int r = i/9, kk = i%9;
    const int pi = mt*16 + r;
    int off = -1;
    if (pi < 625){
      const int y = pi/25, x = pi%25;
      const int ry = y-1+kk/3, cx = x-1+kk%3;
      if (ry>=0 && ry<25 && cx>=0 && cx<25) off = ry*25+cx;
    }
    sOff[r][kk] = off;
  }
  __syncthreads();
  const int wid = tid>>6, lane = tid&63;
  const int ct = (int)blockIdx.y*4 + wid;
  const int row = lane & 15;
  const int koff = (lane>>4)<<3;
  const bf16* wptr = WtM + (((size_t)ct*KS)*64 + lane)*8;
  f32x4 acc0 = {0.f,0.f,0.f,0.f};
  f32x4 acc1 = {0.f,0.f,0.f,0.f};
  for (int kk=0; kk<9; ++kk){
    const int off = sOff[row][kk];
    const bf16* arow = in + (size_t)(off<0?0:off)*CIN + koff;
    #pragma unroll 4
    for (int cs=0; cs<CS; ++cs){
      union { uint4 u; short8 v; } A;
      A.u = make_uint4(0u,0u,0u,0u);
      if (off >= 0) A.u = *(const uint4*)(arow + cs*32);
      union { uint4 u; short8 v; } B;
      B.u = *(const uint4*)wptr;
      wptr += 64*8;
      if ((cs & 1) == 0) acc0 = __builtin_amdgcn_mfma_f32_16x16x32_bf16(A.v, B.v, acc0, 0, 0, 0);
      else               acc1 = __builtin_amdgcn_mfma_f32_16x16x32_bf16(A.v, B.v, acc1, 0, 0, 0);
    }
  }
  f32x4 acc = acc0 + acc1;
  const int c = ct*16 + (lane & 15);
  const float bi = bias[c], gs = gam[c], bs = bet[c];
  #pragma unroll
  for (int j=0;j<4;++j){
    const int r = ((lane>>4)<<2) + j;
    const int pi = mt*16 + r;
    if (pi >= 625) continue;
    float vv = (acc[j]+bi)*gs + bs; vv = vv>0.f?vv:0.f;
    if constexpr (FINAL)
      ((float*)out)[(size_t)c*625 + pi] = vv;
    else
      ((bf16*)out)[(size_t)pi*COUT + c] = __float2bfloat16(vv);
  }
}

// ---------- launch ----------
extern "C" void kernel_launch(void* const* d_in, const int* in_sizes, int n_in,
                              void* d_out, int out_size, void* d_ws, size_t ws_size,
                              hipStream_t stream)
{
  (void)n_in; (void)out_size; (void)ws_size;
  const int N = in_sizes[0] / 5;

  char* p = (char*)d_ws;
  size_t off = 0;
  auto carve = [&](size_t bytes)->char*{
    char* r = p + off;
    off += (bytes + 255) & ~(size_t)255;
    return r;
  };
  // ---- zero region ----
  unsigned*      counters = (unsigned*)     carve(256);
  unsigned*      cnt      = (unsigned*)     carve((size_t)NCELL*4);
  unsigned*      scnt     = (unsigned*)     carve((size_t)MAXVX*4);
  unsigned char* m0       = (unsigned char*)carve(NCELL);
  unsigned char* m1       = (unsigned char*)carve(25000);
  unsigned char* m2       = (unsigned char*)carve(3125);
  bf16*  F0c   = (bf16*) carve((size_t)MAXVX*128*2);
  bf16*  F1    = (bf16*) carve((size_t)NCELL*64*2);     // dense (20,100,100,64)
  bf16*  F2    = (bf16*) carve((size_t)25000*128*2);
  bf16*  F3    = (bf16*) carve((size_t)25000*128*2);
  bf16*  F4    = (bf16*) carve((size_t)3125*256*2);
  bf16*  bev1  = (bf16*) carve((size_t)625*512*2);
  const size_t zero_total = off;
  // ---- non-zero ----
  int*   map      = (int*)  carve((size_t)NCELL*4);      // 0xFF
  int*   keptList = (int*)  carve((size_t)MAXVX*4);
  int*   list0    = (int*)  carve((size_t)MAXVX*4);
  int*   list1    = (int*)  carve((size_t)25000*4);
  int*   list2    = (int*)  carve((size_t)3125*4);
  int*   slots    = (int*)  carve((size_t)MAXVX*CAP*4);
  float* prm      = (float*)carve(8192*4);
  float* z128     = (float*)carve(512);
  bf16*  Wm1      = (bf16*) carve((size_t)64*27*128*2);
  bf16*  Wm2      = (bf16*) carve((size_t)128*27*64*2);
  bf16*  Wm3      = (bf16*) carve((size_t)128*27*128*2);
  bf16*  Wm4      = (bf16*) carve((size_t)256*27*128*2);
  bf16*  WmB1     = (bf16*) carve((size_t)512*9*1280*2);
  bf16*  WmB2     = (bf16*) carve((size_t)256*9*512*2);

  hipMemsetAsync(d_ws, 0, zero_total, stream);
  hipMemsetAsync(map, 0xFF, (size_t)NCELL*4, stream);

  P22 ps;
  const int prmIdx[22] = {1,2,3,4,5,6,7,8, 10,11, 13,14, 16,17, 19,20, 22,23,24, 26,27,28};
  for (int e=0;e<22;++e) ps.p[e] = (const float*)d_in[prmIdx[e]];
  k_params<<<1,256,0,stream>>>(ps, prm);
  k_z128<<<1,128,0,stream>>>(prm, z128);
  k_wtm<<<cdiv(64*27*128,256),256,0,stream>>>((const float*)d_in[9],  Wm1, 64, 128, 27);
  k_wtm<<<cdiv(128*27*64,256),256,0,stream>>>((const float*)d_in[12], Wm2, 128, 64, 27);
  k_wtm<<<cdiv(128*27*128,256),256,0,stream>>>((const float*)d_in[15], Wm3, 128, 128, 27);
  k_wtm<<<cdiv(256*27*128,256),256,0,stream>>>((const float*)d_in[18], Wm4, 256, 128, 27);
  k_wtm<<<cdiv(512*9*1280,256),256,0,stream>>>((const float*)d_in[21], WmB1, 512, 1280, 9);
  k_wtm<<<cdiv(256*9*512,256),256,0,stream>>>((const float*)d_in[25], WmB2, 256, 512, 9);

  const float* pts = (const float*)d_in[0];
  k_points<<<cdiv(N,256),256,0,stream>>>(pts, N, cnt);
  k_rank<<<1,1024,0,stream>>>(cnt, keptList, map, counters);
  k_points2<<<cdiv(N,256),256,0,stream>>>(pts, N, map, scnt, slots);
  k_vfe<<<cdiv(MAXVX,4*VPW),256,0,stream>>>(pts, prm, scnt, slots, keptList, counters,
                                            z128, F0c, m0, list0);

  k_pool<<<cdiv(25000,256),256,0,stream>>>(m0, m1, list1, counters+1, 20,100,100, 10,50,50);
  k_pool<<<cdiv(3125,256),256,0,stream>>>(m1, m2, list2, counters+2, 10,50,50, 5,25,25);

  // sp1: 1Ax4B reg-blocked, compact-in via map -> dense F1
  k_conv3m4<128,64,1,1><<<dim3(cdiv(MAXVX,64),1),256,0,stream>>>(
      F0c, F1, Wm1, prm+O_SP1G, prm+O_SP1B, list0, counters+0, map, 20,100,100, 100,100);
  // sp2: dense F1 -> dense F2 (stride 2)
  k_conv3m4<64,128,2,0><<<dim3(cdiv(25000,64),2),256,0,stream>>>(
      F1, F2, Wm2, prm+O_SP2G, prm+O_SP2B, list1, counters+1, map, 20,100,100, 50,50);
  // sp3: dense F2 -> dense F3
  k_conv3m4<128,128,1,0><<<dim3(cdiv(25000,64),2),256,0,stream>>>(
      F2, F3, Wm3, prm+O_SP3G, prm+O_SP3B, list1, counters+1, map, 10,50,50, 50,50);
  // sp4: small site count -> waves-on-N variant, BEV out
  k_conv3m<128,256,2,0,2><<<dim3(cdiv(3125,16),4),256,0,stream>>>(
      F3, F4, Wm4, prm+O_SP4G, prm+O_SP4B, list2, counters+2, map, 10,50,50, 25,25);

  // BEV head
  k_conv2m<1280,512,false,bf16><<<dim3(40,8),256,0,stream>>>(
      F4, bev1, WmB1, prm+O_BV1B, prm+O_BV1G, prm+O_BV1BT);
  k_conv2m<512,256,true,float><<<dim3(40,4),256,0,stream>>>(
      bev1, (float*)d_out, WmB2, prm+O_BV2B, prm+O_BV2G, prm+O_BV2BT);
}

// Round 14
// 595.924 us; speedup vs baseline: 9.1052x; 1.2562x over previous
//
#include <hip/hip_runtime.h>
#include <hip/hip_bf16.h>
#include <cstdint>
#include <cstddef>

typedef __hip_bfloat16 bf16;
typedef short short8 __attribute__((ext_vector_type(8)));
typedef float f32x4 __attribute__((ext_vector_type(4)));

#define GXC 100
#define GYC 100
#define GZC 20
#define NCELL (GXC*GYC*GZC)
#define MAXVX 60000
#define CAP 12
#define NSCB 196   // scan blocks: 196*1024 >= 200000

static inline int cdiv(int a, int b){ return (a+b-1)/b; }

__device__ __forceinline__ float b2f(bf16 v){ return __bfloat162float(v); }

// ---------- params gather ----------
struct P22 { const float* p[22]; };
__global__ void k_params(P22 ps, float* __restrict__ prm)
{
  const int ns[22] = {160,32,32,32,4096,128,128,128,64,64,128,128,128,128,256,256,512,512,512,256,256,256};
  int off = 0;
  for (int e=0;e<22;++e){
    const float* s = ps.p[e];
    const int n = ns[e];
    for (int i=threadIdx.x;i<n;i+=256) prm[off+i] = s[i];
    off += n;
  }
}
#define O_V1W 0
#define O_V1B 160
#define O_V1G 192
#define O_V1BT 224
#define O_V2W 256
#define O_V2B 4352
#define O_V2G 4480
#define O_V2BT 4608
#define O_SP1G 4736
#define O_SP1B 4800
#define O_SP2G 4864
#define O_SP2B 4992
#define O_SP3G 5120
#define O_SP3B 5248
#define O_SP4G 5376
#define O_SP4B 5632
#define O_BV1B 5888
#define O_BV1G 6400
#define O_BV1BT 6912
#define O_BV2B 7424
#define O_BV2G 7680
#define O_BV2BT 7936

// ---------- voxelize pass 1 ----------
__global__ void k_points(const float* __restrict__ pts, int N, unsigned* __restrict__ cnt)
{
  const int i = blockIdx.x*256 + threadIdx.x;
  if (i >= N) return;
  float x = pts[(size_t)i*5+0];
  float y = pts[(size_t)i*5+1];
  float z = pts[(size_t)i*5+2];
  float qx = (x - (-51.2f)) / 1.024f;
  float qy = (y - (-51.2f)) / 1.024f;
  float qz = (z - (-5.0f))  / 0.4f;
  int gx=(int)floorf(qx), gy=(int)floorf(qy), gz=(int)floorf(qz);
  if (x == 0.0f) return;
  if (gx<0||gx>=GXC||gy<0||gy>=GYC||gz<0||gz>=GZC) return;
  atomicAdd(&cnt[gx*(GYC*GZC) + gy*GZC + gz], 1u);
}

// ---------- 3-phase rank of occupied cells (cell-id order) ----------
__global__ __launch_bounds__(256) void k_scanA(const unsigned* __restrict__ cnt,
                                               int* __restrict__ blockSums)
{
  __shared__ int sd[4];
  const int tid = threadIdx.x;
  const int base = (int)blockIdx.x*1024 + tid*4;
  int t = 0;
  #pragma unroll
  for (int j=0;j<4;++j){
    const int cell = base+j;
    t += (cell<NCELL && cnt[cell]>0u) ? 1 : 0;
  }
  // wave reduce
  #pragma unroll
  for (int o=32;o>0;o>>=1) t += __shfl_down(t, o);
  if ((tid&63)==0) sd[tid>>6]=t;
  __syncthreads();
  if (tid==0) blockSums[blockIdx.x] = sd[0]+sd[1]+sd[2]+sd[3];
}

__global__ __launch_bounds__(256) void k_scanB(const int* __restrict__ blockSums,
                                               int* __restrict__ blockPref,
                                               unsigned* __restrict__ counters)
{
  __shared__ int sd[256];
  const int tid = threadIdx.x;
  int v = (tid < NSCB) ? blockSums[tid] : 0;
  sd[tid]=v; __syncthreads();
  for (int o=1;o<256;o<<=1){
    int x = sd[tid];
    int add = (tid>=o)? sd[tid-o] : 0;
    __syncthreads();
    sd[tid]=x+add;
    __syncthreads();
  }
  if (tid < NSCB) blockPref[tid] = sd[tid]-v;     // exclusive
  if (tid == 255){
    int tot = sd[NSCB-1];
    counters[0] = (unsigned)(tot < MAXVX ? tot : MAXVX);
  }
}

__global__ __launch_bounds__(256) void k_scanC(const unsigned* __restrict__ cnt,
                                               const int* __restrict__ blockPref,
                                               int* __restrict__ keptList,
                                               int* __restrict__ map)
{
  __shared__ int sd[256];
  const int tid = threadIdx.x;
  const int base = (int)blockIdx.x*1024 + tid*4;
  int f[4]; int tsum = 0;
  #pragma unroll
  for (int j=0;j<4;++j){
    const int cell = base+j;
    f[j] = (cell<NCELL && cnt[cell]>0u) ? 1 : 0;
    tsum += f[j];
  }
  sd[tid]=tsum; __syncthreads();
  for (int o=1;o<256;o<<=1){
    int x = sd[tid];
    int add = (tid>=o)? sd[tid-o] : 0;
    __syncthreads();
    sd[tid]=x+add;
    __syncthreads();
  }
  int run = blockPref[blockIdx.x] + sd[tid]-tsum;   // exclusive rank for first of my 4
  #pragma unroll
  for (int j=0;j<4;++j){
    const int cell = base+j;
    if (f[j] && run < MAXVX){
      keptList[run] = cell;
      const int ix=cell/2000, iy=(cell/20)%100, iz=cell%20;
      map[(iz*GYC+iy)*GXC+ix] = run;
    }
    run += f[j];
  }
}

// ---------- voxelize pass 2 ----------
__global__ void k_points2(const float* __restrict__ pts, int N,
                          const int* __restrict__ map,
                          unsigned* __restrict__ scnt, int* __restrict__ slots)
{
  const int i = blockIdx.x*256 + threadIdx.x;
  if (i >= N) return;
  float x = pts[(size_t)i*5+0];
  float y = pts[(size_t)i*5+1];
  float z = pts[(size_t)i*5+2];
  float qx = (x - (-51.2f)) / 1.024f;
  float qy = (y - (-51.2f)) / 1.024f;
  float qz = (z - (-5.0f))  / 0.4f;
  int gx=(int)floorf(qx), gy=(int)floorf(qy), gz=(int)floorf(qz);
  if (x == 0.0f) return;
  if (gx<0||gx>=GXC||gy<0||gy>=GYC||gz<0||gz>=GZC) return;
  const int didx = (gz*GYC+gy)*GXC+gx;
  const int r = map[didx];
  if (r < 0) return;
  unsigned pos = atomicAdd(&scnt[r], 1u);
  if (pos < CAP) slots[r*CAP + pos] = i;
}

// ---------- z128 ----------
__global__ void k_z128(const float* __restrict__ prm, float* __restrict__ z128)
{
  __shared__ float h1[32];
  const int tid = threadIdx.x;   // 128
  if (tid<32){ float s = prm[O_V1B+tid]*prm[O_V1G+tid]+prm[O_V1BT+tid]; h1[tid]=s>0.f?s:0.f; }
  __syncthreads();
  float s = prm[O_V2B+tid];
  for (int j=0;j<32;++j) s += prm[O_V2W+tid*32+j]*h1[j];
  s = s*prm[O_V2G+tid] + prm[O_V2BT+tid];
  z128[tid] = s>0.f?s:0.f;
}

// ---------- VFE: wave-per-voxel ----------
#define VPW 16
__global__ __launch_bounds__(256) void k_vfe(
  const float* __restrict__ pts, const float* __restrict__ prm,
  const unsigned* __restrict__ scnt, const int* __restrict__ slots,
  const int* __restrict__ keptList, const unsigned* __restrict__ counters,
  const float* __restrict__ z128,
  bf16* __restrict__ F0c, unsigned char* __restrict__ m0, int* __restrict__ list0)
{
  __shared__ float sW1[160], sb1[32], sg1[32], sB1[32];
  __shared__ float sW2[128*33];
  __shared__ float sb2[128], sg2[128], sB2[128], sz[128];
  __shared__ int sSrt[4][10];
  const int tid = threadIdx.x;
  for (int i=tid;i<160;i+=256) sW1[i]=prm[O_V1W+i];
  if (tid<32){ sb1[tid]=prm[O_V1B+tid]; sg1[tid]=prm[O_V1G+tid]; sB1[tid]=prm[O_V1BT+tid]; }
  for (int i=tid;i<4096;i+=256) sW2[(i>>5)*33 + (i&31)] = prm[O_V2W+i];
  if (tid<128){ sb2[tid]=prm[O_V2B+tid]; sg2[tid]=prm[O_V2G+tid]; sB2[tid]=prm[O_V2BT+tid]; sz[tid]=z128[tid]; }
  __syncthreads();
  const int wid = tid>>6, lane = tid&63;
  const int n = (int)counters[0];
  const int gid0 = ((int)blockIdx.x*4 + wid)*VPW;
  for (int v=0; v<VPW; ++v){
    const int gid = gid0 + v;
    if (gid >= n) break;
    const int total = (int)scnt[gid];
    const int cc = total<CAP?total:CAP;
    const int np = total<10?total:10;
    int myIdx = 0x7FFFFFFF;
    if (lane < cc) myIdx = slots[gid*CAP + lane];
    int rank = 0;
    for (int s=0;s<cc;++s){
      int vs = __shfl(myIdx, s);
      rank += (vs < myIdx) ? 1 : 0;
    }
    if (lane < cc && rank < np) sSrt[wid][rank] = myIdx;
    float vm0 = 0.f, vm1 = 0.f;
    for (int r=0;r<np;++r){
      const int pi = sSrt[wid][r];
      const float p0 = pts[(size_t)pi*5+0];
      const float p1 = pts[(size_t)pi*5+1];
      const float p2 = pts[(size_t)pi*5+2];
      const float p3 = pts[(size_t)pi*5+3];
      const float p4 = pts[(size_t)pi*5+4];
      float h = 0.f;
      if (lane < 32){
        float s = sb1[lane] + sW1[lane*5+0]*p0 + sW1[lane*5+1]*p1
                + sW1[lane*5+2]*p2 + sW1[lane*5+3]*p3 + sW1[lane*5+4]*p4;
        s = s*sg1[lane]+sB1[lane];
        h = s>0.f?s:0.f;
      }
      float s0 = sb2[lane], s1 = sb2[lane+64];
      #pragma unroll
      for (int j=0;j<32;++j){
        const float hj = __shfl(h, j);
        s0 += sW2[lane*33+j]*hj;
        s1 += sW2[(lane+64)*33+j]*hj;
      }
      s0 = s0*sg2[lane]+sB2[lane];    s0 = s0>0.f?s0:0.f;
      s1 = s1*sg2[lane+64]+sB2[lane+64]; s1 = s1>0.f?s1:0.f;
      vm0 = fmaxf(vm0, s0); vm1 = fmaxf(vm1, s1);
    }
    if (np<10){ vm0 = fmaxf(vm0, sz[lane]); vm1 = fmaxf(vm1, sz[lane+64]); }
    F0c[(size_t)gid*128 + lane]      = __float2bfloat16(vm0);
    F0c[(size_t)gid*128 + lane + 64] = __float2bfloat16(vm1);
    if (lane==0){
      const int cell = keptList[gid];
      const int ix=cell/2000, iy=(cell/20)%100, iz=cell%20;
      const int didx = (iz*GYC+iy)*GXC+ix;
      m0[didx]=1; list0[gid]=didx;
    }
  }
}

// ---------- occupancy pooling ----------
__global__ void k_pool(const unsigned char* __restrict__ mIn, unsigned char* __restrict__ mOut,
                       int* __restrict__ listOut, unsigned* __restrict__ counter,
                       int IZ,int IY,int IX,int OZ,int OY,int OX)
{
  const int s = blockIdx.x*256+threadIdx.x;
  if (s >= OZ*OY*OX) return;
  const int ox=s%OX, oy=(s/OX)%OY, oz=s/(OX*OY);
  bool any=false;
  for (int dz=0;dz<3;++dz){ int nz=oz*2+dz-1; if(nz<0||nz>=IZ)continue;
    for (int dy=0;dy<3;++dy){ int ny=oy*2+dy-1; if(ny<0||ny>=IY)continue;
      for (int dx=0;dx<3;++dx){ int nx=ox*2+dx-1; if(nx<0||nx>=IX)continue;
        any = any || (mIn[(nz*IY+ny)*IX+nx] != 0);
      }}}
  if (any){ mOut[s]=1; unsigned p=atomicAdd(counter,1u); listOut[p]=s; }
}

// ---------- MFMA weight re-layout ----------
__global__ void k_wtm(const float* __restrict__ src, bf16* __restrict__ dst,
                      int COUT, int CIN, int KV)
{
  const int K = KV*CIN;
  const int idx = blockIdx.x*256+threadIdx.x;
  if (idx >= COUT*K) return;
  const int j = idx & 7;
  const int l = (idx >> 3) & 63;
  const int rest = idx >> 9;
  const int KS = K/32;
  const int ks = rest % KS;
  const int ct = rest / KS;
  const int o = ct*16 + (l & 15);
  const int k = ks*32 + ((l>>4)<<3) + j;
  const int kk = k / CIN;
  const int ci = k % CIN;
  dst[idx] = __float2bfloat16(src[((size_t)o*CIN + ci)*KV + kk]);
}

// ---------- MFMA conv, waves-on-M, 1Ax4B ----------
template<int CIN, int COUT, int STRIDE, int INMODE>
__global__ __launch_bounds__(256) void k_conv3m4(
    const bf16* __restrict__ inP, bf16* __restrict__ out,
    const bf16* __restrict__ WtM,
    const float* __restrict__ gam, const float* __restrict__ bet,
    const int* __restrict__ list, const unsigned* __restrict__ nPtr,
    const int* __restrict__ map,
    int IZ, int IY, int IX, int OY, int OX)
{
  constexpr int KS = 27*CIN/32;
  constexpr int CS = CIN/32;
  __shared__ int sMi[64][27];
  __shared__ int sSite[64];
  const int n = (int)(*nPtr);
  const int base = (int)blockIdx.x * 64;
  if (base >= n) return;
  const int tid = threadIdx.x;
  for (int i=tid; i<64*27; i+=256){
    const int r = i/27, kk = i%27;
    int mi = -1, site = -1;
    if (base + r < n){
      site = list[base+r];
      const int ox = site % OX, oy = (site/OX)%OY, oz = site/(OX*OY);
      const int dz=kk/9, dy=(kk/3)%3, dx=kk%3;
      const int nz=oz*STRIDE+dz-1, ny=oy*STRIDE+dy-1, nx=ox*STRIDE+dx-1;
      if (nz>=0&&nz<IZ&&ny>=0&&ny<IY&&nx>=0&&nx<IX){
        const int nd=(nz*IY+ny)*IX+nx;
        mi = (INMODE==1) ? map[nd] : nd;
      }
    }
    if (kk==0) sSite[r] = site;
    sMi[r][kk] = mi;
  }
  __syncthreads();
  const int wid = tid>>6, lane = tid&63;
  const int row = lane & 15;
  const int mrow = wid*16 + row;
  const int koff = (lane>>4)<<3;
  const int ct0 = (int)blockIdx.y*4;
  const bf16* w0 = WtM + (((size_t)(ct0+0)*KS)*64 + lane)*8;
  const bf16* w1 = WtM + (((size_t)(ct0+1)*KS)*64 + lane)*8;
  const bf16* w2 = WtM + (((size_t)(ct0+2)*KS)*64 + lane)*8;
  const bf16* w3 = WtM + (((size_t)(ct0+3)*KS)*64 + lane)*8;
  f32x4 acc0 = {0.f,0.f,0.f,0.f};
  f32x4 acc1 = {0.f,0.f,0.f,0.f};
  f32x4 acc2 = {0.f,0.f,0.f,0.f};
  f32x4 acc3 = {0.f,0.f,0.f,0.f};
  size_t wo = 0;
  for (int kk=0; kk<27; ++kk){
    const int mi = sMi[mrow][kk];
    const bf16* arow = inP + (size_t)(mi<0?0:mi)*CIN + koff;
    #pragma unroll
    for (int cs=0; cs<CS; ++cs){
      union { uint4 u; short8 v; } A;
      A.u = make_uint4(0u,0u,0u,0u);
      if (mi >= 0) A.u = *(const uint4*)(arow + cs*32);
      union { uint4 u; short8 v; } B0, B1, B2, B3;
      B0.u = *(const uint4*)(w0 + wo);
      B1.u = *(const uint4*)(w1 + wo);
      B2.u = *(const uint4*)(w2 + wo);
      B3.u = *(const uint4*)(w3 + wo);
      wo += 64*8;
      acc0 = __builtin_amdgcn_mfma_f32_16x16x32_bf16(A.v, B0.v, acc0, 0, 0, 0);
      acc1 = __builtin_amdgcn_mfma_f32_16x16x32_bf16(A.v, B1.v, acc1, 0, 0, 0);
      acc2 = __builtin_amdgcn_mfma_f32_16x16x32_bf16(A.v, B2.v, acc2, 0, 0, 0);
      acc3 = __builtin_amdgcn_mfma_f32_16x16x32_bf16(A.v, B3.v, acc3, 0, 0, 0);
    }
  }
  #pragma unroll
  for (int q=0;q<4;++q){
    const f32x4 acc = (q==0)?acc0:((q==1)?acc1:((q==2)?acc2:acc3));
    const int c = (ct0+q)*16 + row;
    const float gs = gam[c], bs = bet[c];
    #pragma unroll
    for (int j=0;j<4;++j){
      const int r = ((lane>>4)<<2) + j;
      const int site = sSite[wid*16 + r];
      if (site < 0) continue;
      float vv = acc[j]*gs + bs; vv = vv>0.f?vv:0.f;
      out[(size_t)site*COUT + c] = __float2bfloat16(vv);
    }
  }
}

// ---------- MFMA conv, waves-on-N (small-site layers) ----------
template<int CIN, int COUT, int STRIDE, int INMODE, int OUTMODE>
__global__ __launch_bounds__(256) void k_conv3m(
    const bf16* __restrict__ inP, bf16* __restrict__ out,
    const bf16* __restrict__ WtM,
    const float* __restrict__ gam, const float* __restrict__ bet,
    const int* __restrict__ list, const unsigned* __restrict__ nPtr,
    const int* __restrict__ map,
    int IZ, int IY, int IX, int OY, int OX)
{
  constexpr int KS = 27*CIN/32;
  constexpr int CS = CIN/32;
  __shared__ int sMi[16][27];
  __shared__ int sSite[16];
  const int n = (int)(*nPtr);
  const int base = (int)blockIdx.x * 16;
  if (base >= n) return;
  const int tid = threadIdx.x;
  for (int i=tid; i<16*27; i+=256){
    const int r = i/27, kk = i%27;
    int mi = -1, site = -1;
    if (base + r < n){
      site = list[base+r];
      const int ox = site % OX, oy = (site/OX)%OY, oz = site/(OX*OY);
      const int dz=kk/9, dy=(kk/3)%3, dx=kk%3;
      const int nz=oz*STRIDE+dz-1, ny=oy*STRIDE+dy-1, nx=ox*STRIDE+dx-1;
      if (nz>=0&&nz<IZ&&ny>=0&&ny<IY&&nx>=0&&nx<IX){
        const int nd=(nz*IY+ny)*IX+nx;
        mi = (INMODE==1) ? map[nd] : nd;
      }
    }
    if (kk==0) sSite[r] = site;
    sMi[r][kk] = mi;
  }
  __syncthreads();
  const int wid = tid>>6, lane = tid&63;
  const int ct = (int)blockIdx.y*4 + wid;
  const int row = lane & 15;
  const int koff = (lane>>4)<<3;
  const bf16* wptr = WtM + (((size_t)ct*KS)*64 + lane)*8;
  f32x4 acc0 = {0.f,0.f,0.f,0.f};
  f32x4 acc1 = {0.f,0.f,0.f,0.f};
  for (int kk=0; kk<27; ++kk){
    const int mi = sMi[row][kk];
    const bf16* arow = inP + (size_t)(mi<0?0:mi)*CIN + koff;
    #pragma unroll
    for (int cs=0; cs<CS; ++cs){
      union { uint4 u; short8 v; } A;
      A.u = make_uint4(0u,0u,0u,0u);
      if (mi >= 0) A.u = *(const uint4*)(arow + cs*32);
      union { uint4 u; short8 v; } B;
      B.u = *(const uint4*)wptr;
      wptr += 64*8;
      if ((cs & 1) == 0) acc0 = __builtin_amdgcn_mfma_f32_16x16x32_bf16(A.v, B.v, acc0, 0, 0, 0);
      else               acc1 = __builtin_amdgcn_mfma_f32_16x16x32_bf16(A.v, B.v, acc1, 0, 0, 0);
    }
  }
  f32x4 acc = acc0 + acc1;
  const int c = ct*16 + (lane & 15);
  const float gs = gam[c], bs = bet[c];
  #pragma unroll
  for (int j=0;j<4;++j){
    const int r = ((lane>>4)<<2) + j;
    const int site = sSite[r];
    if (site < 0) continue;
    float vv = acc[j]*gs + bs; vv = vv>0.f?vv:0.f;
    size_t oidx;
    if constexpr (OUTMODE==2){
      const int ox2=site%OX, oy2=(site/OX)%OY, oz2=site/(OX*OY);
      oidx = ((size_t)(oy2*OX+ox2)*5 + oz2)*COUT + c;
    } else {
      oidx = (size_t)site*COUT + c;
    }
    out[oidx] = __float2bfloat16(vv);
  }
}

// ---------- MFMA dense 2D BEV conv ----------
template<int CIN, int COUT, bool FINAL, typename TOUT>
__global__ __launch_bounds__(256) void k_conv2m(
    const bf16* __restrict__ in, TOUT* __restrict__ out,
    const bf16* __restrict__ WtM,
    const float* __restrict__ bias, const float* __restrict__ gam, const float* __restrict__ bet)
{
  constexpr int KS = 9*CIN/32;
  constexpr int CS = CIN/32;
  __shared__ int sOff[16][9];
  const int tid = threadIdx.x;
  const int mt = (int)blockIdx.x;
  for (int i=tid; i<16*9; i+=256){
    const int r = i/9, kk = i%9;
    const int pi = mt*16 + r;
    int off = -1;
    if (pi < 625){
      const int y = pi/25, x = pi%25;
      const int ry = y-1+kk/3, cx = x-1+kk%3;
      if (ry>=0 && ry<25 && cx>=0 && cx<25) off = ry*25+cx;
    }
    sOff[r][kk] = off;
  }
  __syncthreads();
  const int wid = tid>>6, lane = tid&63;
  const int ct = (int)blockIdx.y*4 + wid;
  const int row = lane & 15;
  const int koff = (lane>>4)<<3;
  const bf16* wptr = WtM + (((size_t)ct*KS)*64 + lane)*8;
  f32x4 acc0 = {0.f,0.f,0.f,0.f};
  f32x4 acc1 = {0.f,0.f,0.f,0.f};
  for (int kk=0; kk<9; ++kk){
    const int off = sOff[row][kk];
    const bf16* arow = in + (size_t)(off<0?0:off)*CIN + koff;
    #pragma unroll 4
    for (int cs=0; cs<CS; ++cs){
      union { uint4 u; short8 v; } A;
      A.u = make_uint4(0u,0u,0u,0u);
      if (off >= 0) A.u = *(const uint4*)(arow + cs*32);
      union { uint4 u; short8 v; } B;
      B.u = *(const uint4*)wptr;
      wptr += 64*8;
      if ((cs & 1) == 0) acc0 = __builtin_amdgcn_mfma_f32_16x16x32_bf16(A.v, B.v, acc0, 0, 0, 0);
      else               acc1 = __builtin_amdgcn_mfma_f32_16x16x32_bf16(A.v, B.v, acc1, 0, 0, 0);
    }
  }
  f32x4 acc = acc0 + acc1;
  const int c = ct*16 + (lane & 15);
  const float bi = bias[c], gs = gam[c], bs = bet[c];
  #pragma unroll
  for (int j=0;j<4;++j){
    const int r = ((lane>>4)<<2) + j;
    const int pi = mt*16 + r;
    if (pi >= 625) continue;
    float vv = (acc[j]+bi)*gs + bs; vv = vv>0.f?vv:0.f;
    if constexpr (FINAL)
      ((float*)out)[(size_t)c*625 + pi] = vv;
    else
      ((bf16*)out)[(size_t)pi*COUT + c] = __float2bfloat16(vv);
  }
}

// ---------- launch ----------
extern "C" void kernel_launch(void* const* d_in, const int* in_sizes, int n_in,
                              void* d_out, int out_size, void* d_ws, size_t ws_size,
                              hipStream_t stream)
{
  (void)n_in; (void)out_size; (void)ws_size;
  const int N = in_sizes[0] / 5;

  char* p = (char*)d_ws;
  size_t off = 0;
  auto carve = [&](size_t bytes)->char*{
    char* r = p + off;
    off += (bytes + 255) & ~(size_t)255;
    return r;
  };
  // ---- zero region ----
  unsigned*      counters = (unsigned*)     carve(256);
  unsigned*      cnt      = (unsigned*)     carve((size_t)NCELL*4);
  unsigned*      scnt     = (unsigned*)     carve((size_t)MAXVX*4);
  unsigned char* m0       = (unsigned char*)carve(NCELL);
  unsigned char* m1       = (unsigned char*)carve(25000);
  unsigned char* m2       = (unsigned char*)carve(3125);
  bf16*  F0c   = (bf16*) carve((size_t)MAXVX*128*2);
  bf16*  F1    = (bf16*) carve((size_t)NCELL*64*2);
  bf16*  F2    = (bf16*) carve((size_t)25000*128*2);
  bf16*  F3    = (bf16*) carve((size_t)25000*128*2);
  bf16*  F4    = (bf16*) carve((size_t)3125*256*2);
  bf16*  bev1  = (bf16*) carve((size_t)625*512*2);
  const size_t zero_total = off;
  // ---- non-zero ----
  int*   map      = (int*)  carve((size_t)NCELL*4);      // 0xFF
  int*   keptList = (int*)  carve((size_t)MAXVX*4);
  int*   list0    = (int*)  carve((size_t)MAXVX*4);
  int*   list1    = (int*)  carve((size_t)25000*4);
  int*   list2    = (int*)  carve((size_t)3125*4);
  int*   slots    = (int*)  carve((size_t)MAXVX*CAP*4);
  int*   blockSums= (int*)  carve(NSCB*4);
  int*   blockPref= (int*)  carve(NSCB*4);
  float* prm      = (float*)carve(8192*4);
  float* z128     = (float*)carve(512);
  bf16*  Wm1      = (bf16*) carve((size_t)64*27*128*2);
  bf16*  Wm2      = (bf16*) carve((size_t)128*27*64*2);
  bf16*  Wm3      = (bf16*) carve((size_t)128*27*128*2);
  bf16*  Wm4      = (bf16*) carve((size_t)256*27*128*2);
  bf16*  WmB1     = (bf16*) carve((size_t)512*9*1280*2);
  bf16*  WmB2     = (bf16*) carve((size_t)256*9*512*2);

  hipMemsetAsync(d_ws, 0, zero_total, stream);
  hipMemsetAsync(map, 0xFF, (size_t)NCELL*4, stream);

  P22 ps;
  const int prmIdx[22] = {1,2,3,4,5,6,7,8, 10,11, 13,14, 16,17, 19,20, 22,23,24, 26,27,28};
  for (int e=0;e<22;++e) ps.p[e] = (const float*)d_in[prmIdx[e]];
  k_params<<<1,256,0,stream>>>(ps, prm);
  k_z128<<<1,128,0,stream>>>(prm, z128);
  k_wtm<<<cdiv(64*27*128,256),256,0,stream>>>((const float*)d_in[9],  Wm1, 64, 128, 27);
  k_wtm<<<cdiv(128*27*64,256),256,0,stream>>>((const float*)d_in[12], Wm2, 128, 64, 27);
  k_wtm<<<cdiv(128*27*128,256),256,0,stream>>>((const float*)d_in[15], Wm3, 128, 128, 27);
  k_wtm<<<cdiv(256*27*128,256),256,0,stream>>>((const float*)d_in[18], Wm4, 256, 128, 27);
  k_wtm<<<cdiv(512*9*1280,256),256,0,stream>>>((const float*)d_in[21], WmB1, 512, 1280, 9);
  k_wtm<<<cdiv(256*9*512,256),256,0,stream>>>((const float*)d_in[25], WmB2, 256, 512, 9);

  const float* pts = (const float*)d_in[0];
  k_points<<<cdiv(N,256),256,0,stream>>>(pts, N, cnt);
  k_scanA<<<NSCB,256,0,stream>>>(cnt, blockSums);
  k_scanB<<<1,256,0,stream>>>(blockSums, blockPref, counters);
  k_scanC<<<NSCB,256,0,stream>>>(cnt, blockPref, keptList, map);
  k_points2<<<cdiv(N,256),256,0,stream>>>(pts, N, map, scnt, slots);
  k_vfe<<<cdiv(MAXVX,4*VPW),256,0,stream>>>(pts, prm, scnt, slots, keptList, counters,
                                            z128, F0c, m0, list0);

  k_pool<<<cdiv(25000,256),256,0,stream>>>(m0, m1, list1, counters+1, 20,100,100, 10,50,50);
  k_pool<<<cdiv(3125,256),256,0,stream>>>(m1, m2, list2, counters+2, 10,50,50, 5,25,25);

  // sp1: 1Ax4B reg-blocked, compact-in via map -> dense F1
  k_conv3m4<128,64,1,1><<<dim3(cdiv(MAXVX,64),1),256,0,stream>>>(
      F0c, F1, Wm1, prm+O_SP1G, prm+O_SP1B, list0, counters+0, map, 20,100,100, 100,100);
  // sp2: dense F1 -> dense F2 (stride 2)
  k_conv3m4<64,128,2,0><<<dim3(cdiv(25000,64),2),256,0,stream>>>(
      F1, F2, Wm2, prm+O_SP2G, prm+O_SP2B, list1, counters+1, map, 20,100,100, 50,50);
  // sp3: dense F2 -> dense F3
  k_conv3m4<128,128,1,0><<<dim3(cdiv(25000,64),2),256,0,stream>>>(
      F2, F3, Wm3, prm+O_SP3G, prm+O_SP3B, list1, counters+1, map, 10,50,50, 50,50);
  // sp4: small site count -> waves-on-N variant, BEV out
  k_conv3m<128,256,2,0,2><<<dim3(cdiv(3125,16),4),256,0,stream>>>(
      F3, F4, Wm4, prm+O_SP4G, prm+O_SP4B, list2, counters+2, map, 10,50,50, 25,25);

  // BEV head
  k_conv2m<1280,512,false,bf16><<<dim3(40,8),256,0,stream>>>(
      F4, bev1, WmB1, prm+O_BV1B, prm+O_BV1G, prm+O_BV1BT);
  k_conv2m<512,256,true,float><<<dim3(40,4),256,0,stream>>>(
      bev1, (float*)d_out, WmB2, prm+O_BV2B, prm+O_BV2G, prm+O_BV2BT);
}